// Round 1
// baseline (1416.263 us; speedup 1.0000x reference)
//
#include <hip/hip_runtime.h>
#include <cstddef>

#define N_SH 1195
#define N_SS 390
#define N_HH 805
#define DIM  64

// ---------------- adjacency build (counts; exact & order-independent) -------
__global__ void build_adj_kernel(const int* __restrict__ ei, int E,
                                 float* __restrict__ A, int N) {
    int i = blockIdx.x * blockDim.x + threadIdx.x;
    if (i < E) {
        int src = ei[i];        // row 0 of [2,E]
        int dst = ei[E + i];    // row 1
        atomicAdd(&A[(size_t)dst * N + src], 1.0f);
    }
}

// row sums -> reciprocal; use_max1: 1/max(s,1) (GCN mean), else 1/s (pre_sum)
__global__ void rowsum_inv_kernel(const float* __restrict__ X, int M, int K,
                                  float* __restrict__ inv, int use_max1) {
    int row  = blockIdx.x * (blockDim.x / 64) + (threadIdx.x / 64);
    int lane = threadIdx.x & 63;
    if (row >= M) return;
    const float* p = X + (size_t)row * K;
    float s = 0.f;
    for (int c = lane; c < K; c += 64) s += p[c];
    for (int off = 32; off > 0; off >>= 1) s += __shfl_down(s, off);
    if (lane == 0) {
        float d = use_max1 ? fmaxf(s, 1.0f) : s;
        inv[row] = 1.0f / d;
    }
}

// ---------------- generic fp32 GEMM: C = act((A@B + bias) * rowScale) -------
#define BM 64
#define BN 64
#define BK 16

__global__ __launch_bounds__(256) void gemm_kernel(
    const float* __restrict__ A, const float* __restrict__ B,
    const float* __restrict__ bias, const float* __restrict__ rowScale,
    float* __restrict__ C, int M, int N, int K, int act)
{
    __shared__ float As[BK][BM + 4];   // +4 keeps float4 alignment, spreads banks
    __shared__ float Bs[BK][BN];
    const int tid  = threadIdx.x;
    const int row0 = blockIdx.y * BM;
    const int col0 = blockIdx.x * BN;
    const int tr  = (tid >> 4) << 2;   // 0..60
    const int tc  = (tid & 15) << 2;   // 0..60
    const int lar = tid >> 2;          // 0..63  (A row in tile)
    const int lac = (tid & 3) << 2;    // 0,4,8,12 (A k in tile)
    const int lbr = tid >> 4;          // 0..15  (B k in tile)
    const int lbc = (tid & 15) << 2;   // 0..60  (B col in tile)

    float acc[4][4] = {{0.f}};

    for (int k0 = 0; k0 < K; k0 += BK) {
        const int gr = row0 + lar;
        const float* Ap = A + (size_t)gr * K + k0 + lac;
        #pragma unroll
        for (int i = 0; i < 4; ++i) {
            int gk = k0 + lac + i;
            As[lac + i][lar] = (gr < M && gk < K) ? Ap[i] : 0.f;
        }
        const int gk = k0 + lbr;
        const float* Bp = B + (size_t)gk * N + col0 + lbc;
        #pragma unroll
        for (int i = 0; i < 4; ++i) {
            int gc = col0 + lbc + i;
            Bs[lbr][lbc + i] = (gk < K && gc < N) ? Bp[i] : 0.f;
        }
        __syncthreads();
        #pragma unroll
        for (int kk = 0; kk < BK; ++kk) {
            float4 a = *reinterpret_cast<const float4*>(&As[kk][tr]);
            float4 b = *reinterpret_cast<const float4*>(&Bs[kk][tc]);
            acc[0][0] += a.x * b.x; acc[0][1] += a.x * b.y; acc[0][2] += a.x * b.z; acc[0][3] += a.x * b.w;
            acc[1][0] += a.y * b.x; acc[1][1] += a.y * b.y; acc[1][2] += a.y * b.z; acc[1][3] += a.y * b.w;
            acc[2][0] += a.z * b.x; acc[2][1] += a.z * b.y; acc[2][2] += a.z * b.z; acc[2][3] += a.z * b.w;
            acc[3][0] += a.w * b.x; acc[3][1] += a.w * b.y; acc[3][2] += a.w * b.z; acc[3][3] += a.w * b.w;
        }
        __syncthreads();
    }

    #pragma unroll
    for (int i = 0; i < 4; ++i) {
        int gr = row0 + tr + i;
        if (gr >= M) continue;
        float rs = rowScale ? rowScale[gr] : 1.0f;
        #pragma unroll
        for (int j = 0; j < 4; ++j) {
            int gc = col0 + tc + j;
            if (gc >= N) continue;
            float v = acc[i][j];
            if (bias) v += bias[gc];
            v *= rs;
            if (act == 1) v = tanhf(v);
            C[(size_t)gr * N + gc] = v;
        }
    }
}

// ---------------- elementwise helpers ---------------------------------------
__global__ void avg3_kernel(const float* __restrict__ a, const float* __restrict__ b,
                            const float* __restrict__ c, float* __restrict__ o, int n) {
    int i = blockIdx.x * blockDim.x + threadIdx.x;
    if (i < n) o[i] = (a[i] + b[i] + c[i]) / 3.0f;
}

__global__ void add2_kernel(const float* __restrict__ a, const float* __restrict__ b,
                            float* __restrict__ o, int n) {
    int i = blockIdx.x * blockDim.x + threadIdx.x;
    if (i < n) o[i] = a[i] + b[i];
}

__global__ void concat_hh_kernel(const float* __restrict__ emb, const float* __restrict__ kg,
                                 float* __restrict__ out) {
    int i = blockIdx.x * blockDim.x + threadIdx.x;
    const int n = N_HH * 91;
    if (i >= n) return;
    int r = i / 91, c = i % 91;
    out[i] = (c < DIM) ? emb[r * DIM + c] : kg[r * 27 + (c - DIM)];
}

__global__ void transpose_kernel(const float* __restrict__ in, float* __restrict__ out,
                                 int R, int C) {
    int i = blockIdx.x * blockDim.x + threadIdx.x;
    if (i < R * C) {
        int r = i / C, c = i % C;
        out[(size_t)c * R + r] = in[i];
    }
}

// ---------------- BatchNorm (train mode, biased stats), N=256 cols ----------
__global__ void bn_stats_kernel(const float* __restrict__ X, int M,
                                float* __restrict__ stats) {
    int j = threadIdx.x;  // 256 columns
    float s = 0.f, ss = 0.f;
    for (int r = blockIdx.x; r < M; r += gridDim.x) {
        float v = X[(size_t)r * 256 + j];
        s += v; ss += v * v;
    }
    atomicAdd(&stats[j], s);
    atomicAdd(&stats[256 + j], ss);
}

// act: 1 = tanh, 2 = relu
__global__ void bn_apply_kernel(const float* __restrict__ X, const float* __restrict__ stats,
                                const float* __restrict__ g, const float* __restrict__ be,
                                int M, float* __restrict__ out, int act) {
    long long i = (long long)blockIdx.x * blockDim.x + threadIdx.x;
    long long n = (long long)M * 256;
    if (i >= n) return;
    int j = (int)(i & 255);
    float invM = 1.0f / (float)M;
    float mean = stats[j] * invM;
    float var  = fmaxf(stats[256 + j] * invM - mean * mean, 0.f);
    float y = (X[i] - mean) * rsqrtf(var + 1e-5f) * g[j] + be[j];
    out[i] = (act == 1) ? tanhf(y) : fmaxf(y, 0.f);
}

// ---------------- driver -----------------------------------------------------
extern "C" void kernel_launch(void* const* d_in, const int* in_sizes, int n_in,
                              void* d_out, int out_size, void* d_ws, size_t ws_size,
                              hipStream_t stream) {
    const int*   eiSH = (const int*)d_in[1];
    const int*   eiSS = (const int*)d_in[3];
    const int*   eiHH = (const int*)d_in[5];
    const float* P    = (const float*)d_in[6];
    const float* kg   = (const float*)d_in[7];
    const float* emb  = (const float*)d_in[8];
    const float* w_sh1  = (const float*)d_in[9];   const float* b_sh1  = (const float*)d_in[10];
    const float* w_sh2  = (const float*)d_in[11];  const float* b_sh2  = (const float*)d_in[12];
    const float* w_mlp1 = (const float*)d_in[13];  const float* b_mlp1 = (const float*)d_in[14];
    const float* g_bn1  = (const float*)d_in[15];  const float* be_bn1 = (const float*)d_in[16];
    const float* w_sh1h = (const float*)d_in[17];  const float* b_sh1h = (const float*)d_in[18];
    const float* w_sh2h = (const float*)d_in[19];  const float* b_sh2h = (const float*)d_in[20];
    const float* w_mlp1h= (const float*)d_in[21];  const float* b_mlp1h= (const float*)d_in[22];
    const float* g_bn1h = (const float*)d_in[23];  const float* be_bn1h= (const float*)d_in[24];
    const float* w_ss   = (const float*)d_in[25];  const float* b_ss   = (const float*)d_in[26];
    const float* w_hh   = (const float*)d_in[27];  const float* b_hh   = (const float*)d_in[28];
    const float* w_mlp  = (const float*)d_in[29];  const float* b_mlp  = (const float*)d_in[30];
    const float* g_si   = (const float*)d_in[31];  const float* be_si  = (const float*)d_in[32];
    float* out = (float*)d_out;

    const int E_SH = in_sizes[1] / 2;
    const int E_SS = in_sizes[3] / 2;
    const int E_HH = in_sizes[5] / 2;
    const int B    = in_sizes[6] / N_SS;   // 20000

    float* w = (float*)d_ws;
    size_t off = 0;
    auto alloc = [&](size_t n) { float* p = w + off; off += n; return p; };
    float* adjSH   = alloc((size_t)N_SH * N_SH);
    float* adjSS   = alloc((size_t)N_SS * N_SS);
    float* adjHH   = alloc((size_t)N_HH * N_HH);
    float* cntInv  = alloc(N_SH);
    float* presInv = alloc(B);
    float* stats   = alloc(512);
    float* tmpH    = alloc((size_t)N_SH * 256);
    float* x2      = alloc((size_t)N_SH * DIM);
    float* x6      = alloc((size_t)N_SH * DIM);
    float* x9a     = alloc((size_t)N_SH * DIM);
    float* x9      = alloc((size_t)N_SH * 256);
    float* x99     = alloc((size_t)N_SH * 256);
    float* ss1     = alloc((size_t)N_SS * 256);
    float* hh1     = alloc((size_t)N_HH * 256);
    float* xhh0    = alloc((size_t)N_HH * 91);
    float* es      = alloc((size_t)N_SS * 256);
    float* eh      = alloc((size_t)N_HH * 256);
    float* ehT     = alloc((size_t)N_HH * 256);
    float* bufE    = alloc((size_t)B * 256);
    float* bufM    = alloc((size_t)B * 256);
    (void)ws_size; (void)n_in; (void)out_size;

    auto gemm = [&](const float* Am, const float* Bm, const float* bias, const float* rs,
                    float* C, int M, int N, int K, int act) {
        dim3 g((N + BN - 1) / BN, (M + BM - 1) / BM);
        gemm_kernel<<<g, 256, 0, stream>>>(Am, Bm, bias, rs, C, M, N, K, act);
    };

    // adjacency matrices (zero then count)
    hipMemsetAsync(adjSH, 0,
                   ((size_t)N_SH * N_SH + (size_t)N_SS * N_SS + (size_t)N_HH * N_HH) * sizeof(float),
                   stream);
    build_adj_kernel<<<(E_SH + 255) / 256, 256, 0, stream>>>(eiSH, E_SH, adjSH, N_SH);
    build_adj_kernel<<<(E_SS + 255) / 256, 256, 0, stream>>>(eiSS, E_SS, adjSS, N_SS);
    build_adj_kernel<<<(E_HH + 255) / 256, 256, 0, stream>>>(eiHH, E_HH, adjHH, N_HH);
    rowsum_inv_kernel<<<(N_SH + 3) / 4, 256, 0, stream>>>(adjSH, N_SH, N_SH, cntInv, 1);

    // ---- symptom branch (SH graph, mean agg) ----
    gemm(emb, w_sh1, b_sh1, nullptr, tmpH, N_SH, DIM, DIM, 0);
    gemm(adjSH, tmpH, nullptr, cntInv, x2, N_SH, DIM, N_SH, 1);
    gemm(x2, w_sh2, b_sh2, nullptr, tmpH, N_SH, DIM, DIM, 0);
    gemm(adjSH, tmpH, nullptr, cntInv, x6, N_SH, DIM, N_SH, 1);
    int nEl = N_SH * DIM;
    avg3_kernel<<<(nEl + 255) / 256, 256, 0, stream>>>(emb, x2, x6, x9a, nEl);
    gemm(x9a, w_mlp1, b_mlp1, nullptr, tmpH, N_SH, 256, DIM, 0);
    hipMemsetAsync(stats, 0, 512 * sizeof(float), stream);
    bn_stats_kernel<<<64, 256, 0, stream>>>(tmpH, N_SH, stats);
    bn_apply_kernel<<<(N_SH * 256 + 255) / 256, 256, 0, stream>>>(tmpH, stats, g_bn1, be_bn1, N_SH, x9, 1);

    // ---- herb branch (reuses x2/x6/x9a/tmpH) ----
    gemm(emb, w_sh1h, b_sh1h, nullptr, tmpH, N_SH, DIM, DIM, 0);
    gemm(adjSH, tmpH, nullptr, cntInv, x2, N_SH, DIM, N_SH, 1);
    gemm(x2, w_sh2h, b_sh2h, nullptr, tmpH, N_SH, DIM, DIM, 0);
    gemm(adjSH, tmpH, nullptr, cntInv, x6, N_SH, DIM, N_SH, 1);
    avg3_kernel<<<(nEl + 255) / 256, 256, 0, stream>>>(emb, x2, x6, x9a, nEl);
    gemm(x9a, w_mlp1h, b_mlp1h, nullptr, tmpH, N_SH, 256, DIM, 0);
    hipMemsetAsync(stats, 0, 512 * sizeof(float), stream);
    bn_stats_kernel<<<64, 256, 0, stream>>>(tmpH, N_SH, stats);
    bn_apply_kernel<<<(N_SH * 256 + 255) / 256, 256, 0, stream>>>(tmpH, stats, g_bn1h, be_bn1h, N_SH, x99, 1);

    // ---- SS graph (add agg) ----
    gemm(emb, w_ss, b_ss, nullptr, tmpH, N_SS, 256, DIM, 0);
    gemm(adjSS, tmpH, nullptr, nullptr, ss1, N_SS, 256, N_SS, 1);

    // ---- HH graph (concat kgOneHot, add agg) ----
    concat_hh_kernel<<<(N_HH * 91 + 255) / 256, 256, 0, stream>>>(emb, kg, xhh0);
    gemm(xhh0, w_hh, b_hh, nullptr, tmpH, N_HH, 256, 91, 0);
    gemm(adjHH, tmpH, nullptr, nullptr, hh1, N_HH, 256, N_HH, 1);

    // ---- es / eh ----
    add2_kernel<<<(N_SS * 256 + 255) / 256, 256, 0, stream>>>(x9, ss1, es, N_SS * 256);
    add2_kernel<<<(N_HH * 256 + 255) / 256, 256, 0, stream>>>(x99 + (size_t)N_SS * 256, hh1, eh, N_HH * 256);
    transpose_kernel<<<(N_HH * 256 + 255) / 256, 256, 0, stream>>>(eh, ehT, N_HH, 256);

    // ---- prescription path ----
    rowsum_inv_kernel<<<(B + 3) / 4, 256, 0, stream>>>(P, B, N_SS, presInv, 0);
    gemm(P, es, nullptr, presInv, bufE, B, 256, N_SS, 0);
    gemm(bufE, w_mlp, b_mlp, nullptr, bufM, B, 256, 256, 0);
    hipMemsetAsync(stats, 0, 512 * sizeof(float), stream);
    bn_stats_kernel<<<256, 256, 0, stream>>>(bufM, B, stats);
    bn_apply_kernel<<<(B * 256 + 255) / 256, 256, 0, stream>>>(bufM, stats, g_si, be_si, B, bufE, 2);
    gemm(bufE, ehT, nullptr, nullptr, out, B, N_HH, 256, 0);
}

// Round 3
// 1071.320 us; speedup vs baseline: 1.3220x; 1.3220x over previous
//
#include <hip/hip_runtime.h>
#include <cstddef>
#include <cstdint>

#define N_SH 1195
#define N_SS 390
#define N_HH 805
#define DIM  64

typedef __bf16 bf16_t;
typedef bf16_t bf16x4v __attribute__((ext_vector_type(4)));
typedef bf16_t bf16x8v __attribute__((ext_vector_type(8)));
typedef float f32x4 __attribute__((ext_vector_type(4)));

__device__ inline ushort f2bf(float f) {
    union { float f; uint32_t u; } c; c.f = f;
    uint32_t u = c.u;
    u += 0x7FFFu + ((u >> 16) & 1u);
    return (ushort)(u >> 16);
}

// ---------------- adjacency build (counts; exact & order-independent) -------
__global__ void build_adj_kernel(const int* __restrict__ ei, int E,
                                 float* __restrict__ A, int N) {
    int i = blockIdx.x * blockDim.x + threadIdx.x;
    if (i < E) {
        int src = ei[i];
        int dst = ei[E + i];
        atomicAdd(&A[(size_t)dst * N + src], 1.0f);
    }
}

__global__ void rowsum_inv_kernel(const float* __restrict__ X, int M, int K,
                                  float* __restrict__ inv, int use_max1) {
    int row  = blockIdx.x * (blockDim.x / 64) + (threadIdx.x / 64);
    int lane = threadIdx.x & 63;
    if (row >= M) return;
    const float* p = X + (size_t)row * K;
    float s = 0.f;
    for (int c = lane; c < K; c += 64) s += p[c];
    for (int off = 32; off > 0; off >>= 1) s += __shfl_down(s, off);
    if (lane == 0) {
        float d = use_max1 ? fmaxf(s, 1.0f) : s;
        inv[row] = 1.0f / d;
    }
}

// ---------------- fp32 GEMM (small graph-path matrices) ---------------------
#define BM 64
#define BN 64
#define BK 16

__global__ __launch_bounds__(256) void gemm_kernel(
    const float* __restrict__ A, const float* __restrict__ B,
    const float* __restrict__ bias, const float* __restrict__ rowScale,
    float* __restrict__ C, int M, int N, int K, int act)
{
    __shared__ float As[BK][BM + 4];
    __shared__ float Bs[BK][BN];
    const int tid  = threadIdx.x;
    const int row0 = blockIdx.y * BM;
    const int col0 = blockIdx.x * BN;
    const int tr  = (tid >> 4) << 2;
    const int tc  = (tid & 15) << 2;
    const int lar = tid >> 2;
    const int lac = (tid & 3) << 2;
    const int lbr = tid >> 4;
    const int lbc = (tid & 15) << 2;

    float acc[4][4] = {{0.f}};

    for (int k0 = 0; k0 < K; k0 += BK) {
        const int gr = row0 + lar;
        const float* Ap = A + (size_t)gr * K + k0 + lac;
        #pragma unroll
        for (int i = 0; i < 4; ++i) {
            int gk = k0 + lac + i;
            As[lac + i][lar] = (gr < M && gk < K) ? Ap[i] : 0.f;
        }
        const int gk = k0 + lbr;
        const float* Bp = B + (size_t)gk * N + col0 + lbc;
        #pragma unroll
        for (int i = 0; i < 4; ++i) {
            int gc = col0 + lbc + i;
            Bs[lbr][lbc + i] = (gk < K && gc < N) ? Bp[i] : 0.f;
        }
        __syncthreads();
        #pragma unroll
        for (int kk = 0; kk < BK; ++kk) {
            float4 a = *reinterpret_cast<const float4*>(&As[kk][tr]);
            float4 b = *reinterpret_cast<const float4*>(&Bs[kk][tc]);
            acc[0][0] += a.x * b.x; acc[0][1] += a.x * b.y; acc[0][2] += a.x * b.z; acc[0][3] += a.x * b.w;
            acc[1][0] += a.y * b.x; acc[1][1] += a.y * b.y; acc[1][2] += a.y * b.z; acc[1][3] += a.y * b.w;
            acc[2][0] += a.z * b.x; acc[2][1] += a.z * b.y; acc[2][2] += a.z * b.z; acc[2][3] += a.z * b.w;
            acc[3][0] += a.w * b.x; acc[3][1] += a.w * b.y; acc[3][2] += a.w * b.z; acc[3][3] += a.w * b.w;
        }
        __syncthreads();
    }

    #pragma unroll
    for (int i = 0; i < 4; ++i) {
        int gr = row0 + tr + i;
        if (gr >= M) continue;
        float rs = rowScale ? rowScale[gr] : 1.0f;
        #pragma unroll
        for (int j = 0; j < 4; ++j) {
            int gc = col0 + tc + j;
            if (gc >= N) continue;
            float v = acc[i][j];
            if (bias) v += bias[gc];
            v *= rs;
            if (act == 1) v = tanhf(v);
            C[(size_t)gr * N + gc] = v;
        }
    }
}

// ---------------- bf16 MFMA GEMM: 128x128 tile, BK=32, 4 waves --------------
// A: [..][lda] bf16 row-major. Bt: [Np][lda] bf16 (B transposed, row n = col n).
// out = (A@B + bias) * rowScale.
//   outF != 0            -> fp32 write
//   outB != 0, outLo == 0 -> bf16 write
//   outB != 0, outLo != 0 -> hi/lo bf16 split write (outLo same ldo)
#define LDT 40   // LDS row stride (bf16 elems): 32 + 8 pad

__global__ __launch_bounds__(256) void mfma_gemm_kernel(
    const ushort* __restrict__ A, const ushort* __restrict__ Bt,
    int M, int Nw, int K, int lda,
    const float* __restrict__ bias, const float* __restrict__ rowScale,
    float* __restrict__ outF, ushort* __restrict__ outB, ushort* __restrict__ outLo,
    int ldo)
{
    __shared__ __align__(16) ushort As[128 * LDT];
    __shared__ __align__(16) ushort Bs[128 * LDT];
    const int tid  = threadIdx.x;
    const int row0 = blockIdx.y * 128;
    const int col0 = blockIdx.x * 128;
    const int wid  = tid >> 6, lane = tid & 63;
    const int wr = wid >> 1, wc = wid & 1;
    const int l15 = lane & 15, lg = lane >> 4;
    const int kg = lg * 4;

    const int sr = tid >> 2;
    const int sc = (tid & 3) * 8;

    f32x4 acc[4][4];
    #pragma unroll
    for (int m = 0; m < 4; ++m)
        #pragma unroll
        for (int n = 0; n < 4; ++n) acc[m][n] = (f32x4)0.f;

    for (int k0 = 0; k0 < K; k0 += 32) {
        const ushort* ga0 = A  + (size_t)(row0 + sr)      * lda + k0 + sc;
        const ushort* ga1 = A  + (size_t)(row0 + sr + 64) * lda + k0 + sc;
        const ushort* gb0 = Bt + (size_t)(col0 + sr)      * lda + k0 + sc;
        const ushort* gb1 = Bt + (size_t)(col0 + sr + 64) * lda + k0 + sc;
        *reinterpret_cast<uint4*>(&As[sr * LDT + sc])        = *reinterpret_cast<const uint4*>(ga0);
        *reinterpret_cast<uint4*>(&As[(sr + 64) * LDT + sc]) = *reinterpret_cast<const uint4*>(ga1);
        *reinterpret_cast<uint4*>(&Bs[sr * LDT + sc])        = *reinterpret_cast<const uint4*>(gb0);
        *reinterpret_cast<uint4*>(&Bs[(sr + 64) * LDT + sc]) = *reinterpret_cast<const uint4*>(gb1);
        __syncthreads();

        bf16x8v af[4], bfr[4];
        #pragma unroll
        for (int m = 0; m < 4; ++m) {
            int ar = wr * 64 + m * 16 + l15;
            bf16x4v lo = *reinterpret_cast<const bf16x4v*>(&As[ar * LDT + kg]);
            bf16x4v hi = *reinterpret_cast<const bf16x4v*>(&As[ar * LDT + kg + 16]);
            af[m] = __builtin_shufflevector(lo, hi, 0, 1, 2, 3, 4, 5, 6, 7);
        }
        #pragma unroll
        for (int n = 0; n < 4; ++n) {
            int br = wc * 64 + n * 16 + l15;
            bf16x4v lo = *reinterpret_cast<const bf16x4v*>(&Bs[br * LDT + kg]);
            bf16x4v hi = *reinterpret_cast<const bf16x4v*>(&Bs[br * LDT + kg + 16]);
            bfr[n] = __builtin_shufflevector(lo, hi, 0, 1, 2, 3, 4, 5, 6, 7);
        }
        #pragma unroll
        for (int m = 0; m < 4; ++m)
            #pragma unroll
            for (int n = 0; n < 4; ++n)
                acc[m][n] = __builtin_amdgcn_mfma_f32_16x16x32_bf16(af[m], bfr[n], acc[m][n], 0, 0, 0);
        __syncthreads();
    }

    #pragma unroll
    for (int m = 0; m < 4; ++m) {
        int grow_base = row0 + wr * 64 + m * 16 + kg;
        #pragma unroll
        for (int j = 0; j < 4; ++j) {
            int grow = grow_base + j;
            if (grow >= M) continue;
            float rs = rowScale ? rowScale[grow] : 1.0f;
            #pragma unroll
            for (int n = 0; n < 4; ++n) {
                int gcol = col0 + wc * 64 + n * 16 + l15;
                if (gcol >= Nw) continue;
                float v = acc[m][n][j];
                if (bias) v += bias[gcol];
                v *= rs;
                if (outB) {
                    ushort h = f2bf(v);
                    outB[(size_t)grow * ldo + gcol] = h;
                    if (outLo) {
                        float hv = __uint_as_float(((uint32_t)h) << 16);
                        outLo[(size_t)grow * ldo + gcol] = f2bf(v - hv);
                    }
                } else {
                    outF[(size_t)grow * ldo + gcol] = v;
                }
            }
        }
    }
}

// ---------------- conversion / fusion helpers -------------------------------
__global__ void cvt_pad_kernel(const float* __restrict__ in, int R, int C,
                               ushort* __restrict__ out, int Cp) {
    long long i = (long long)blockIdx.x * blockDim.x + threadIdx.x;
    long long n = (long long)R * Cp;
    if (i >= n) return;
    int r = (int)(i / Cp), c = (int)(i % Cp);
    float v = (c < C) ? in[(size_t)r * C + c] : 0.f;
    out[i] = f2bf(v);
}

// es^T bf16 [256][416]: es = x9[:N_SS] + ss1, transposed, k-padded
__global__ void make_esbt_kernel(const float* __restrict__ x9, const float* __restrict__ ss1,
                                 ushort* __restrict__ out, int Kp) {
    int i = blockIdx.x * blockDim.x + threadIdx.x;
    if (i >= 256 * Kp) return;
    int n = i / Kp, k = i % Kp;
    float v = (k < N_SS) ? (x9[(size_t)k * 256 + n] + ss1[(size_t)k * 256 + n]) : 0.f;
    out[i] = f2bf(v);
}

// w_mlp^T duplicated: [256][512], Bt2[n][k] = w_mlp[k&255][n]
__global__ void make_wmlp2_kernel(const float* __restrict__ wm, ushort* __restrict__ out) {
    int i = blockIdx.x * blockDim.x + threadIdx.x;
    if (i >= 256 * 512) return;
    int n = i >> 9, k = i & 511;
    out[i] = f2bf(wm[(size_t)(k & 255) * 256 + n]);
}

// eh bf16 [Rp][256]: eh = x99[N_SS:] + hh1, row-padded with zeros
__global__ void make_ehb_kernel(const float* __restrict__ x99, const float* __restrict__ hh1,
                                ushort* __restrict__ out, int Rp) {
    int i = blockIdx.x * blockDim.x + threadIdx.x;
    if (i >= Rp * 256) return;
    int r = i >> 8, c = i & 255;
    float v = (r < N_HH) ? (x99[(size_t)(N_SS + r) * 256 + c] + hh1[(size_t)r * 256 + c]) : 0.f;
    out[i] = f2bf(v);
}

__global__ void avg3_kernel(const float* __restrict__ a, const float* __restrict__ b,
                            const float* __restrict__ c, float* __restrict__ o, int n) {
    int i = blockIdx.x * blockDim.x + threadIdx.x;
    if (i < n) o[i] = (a[i] + b[i] + c[i]) / 3.0f;
}

__global__ void concat_hh_kernel(const float* __restrict__ emb, const float* __restrict__ kg,
                                 float* __restrict__ out) {
    int i = blockIdx.x * blockDim.x + threadIdx.x;
    const int n = N_HH * 91;
    if (i >= n) return;
    int r = i / 91, c = i % 91;
    out[i] = (c < DIM) ? emb[r * DIM + c] : kg[r * 27 + (c - DIM)];
}

// ---------------- BatchNorm (train mode, biased stats), 256 cols ------------
__global__ void bn_stats_kernel(const float* __restrict__ X, int M,
                                float* __restrict__ stats) {
    int j = threadIdx.x;
    float s = 0.f, ss = 0.f;
    for (int r = blockIdx.x; r < M; r += gridDim.x) {
        float v = X[(size_t)r * 256 + j];
        s += v; ss += v * v;
    }
    atomicAdd(&stats[j], s);
    atomicAdd(&stats[256 + j], ss);
}

__global__ void bn_apply_kernel(const float* __restrict__ X, const float* __restrict__ stats,
                                const float* __restrict__ g, const float* __restrict__ be,
                                int M, float* __restrict__ out, int act) {
    long long i = (long long)blockIdx.x * blockDim.x + threadIdx.x;
    long long n = (long long)M * 256;
    if (i >= n) return;
    int j = (int)(i & 255);
    float invM = 1.0f / (float)M;
    float mean = stats[j] * invM;
    float var  = fmaxf(stats[256 + j] * invM - mean * mean, 0.f);
    float y = (X[i] - mean) * rsqrtf(var + 1e-5f) * g[j] + be[j];
    out[i] = (act == 1) ? tanhf(y) : fmaxf(y, 0.f);
}

// relu(BN(x)) -> bf16
__global__ void bn_apply_bf16_kernel(const float* __restrict__ X, const float* __restrict__ stats,
                                     const float* __restrict__ g, const float* __restrict__ be,
                                     int M, ushort* __restrict__ out) {
    long long i = (long long)blockIdx.x * blockDim.x + threadIdx.x;
    long long n = (long long)M * 256;
    if (i >= n) return;
    int j = (int)(i & 255);
    float invM = 1.0f / (float)M;
    float mean = stats[j] * invM;
    float var  = fmaxf(stats[256 + j] * invM - mean * mean, 0.f);
    float y = (X[i] - mean) * rsqrtf(var + 1e-5f) * g[j] + be[j];
    out[i] = f2bf(fmaxf(y, 0.f));
}

// ---------------- driver -----------------------------------------------------
extern "C" void kernel_launch(void* const* d_in, const int* in_sizes, int n_in,
                              void* d_out, int out_size, void* d_ws, size_t ws_size,
                              hipStream_t stream) {
    const int*   eiSH = (const int*)d_in[1];
    const int*   eiSS = (const int*)d_in[3];
    const int*   eiHH = (const int*)d_in[5];
    const float* P    = (const float*)d_in[6];
    const float* kg   = (const float*)d_in[7];
    const float* emb  = (const float*)d_in[8];
    const float* w_sh1  = (const float*)d_in[9];   const float* b_sh1  = (const float*)d_in[10];
    const float* w_sh2  = (const float*)d_in[11];  const float* b_sh2  = (const float*)d_in[12];
    const float* w_mlp1 = (const float*)d_in[13];  const float* b_mlp1 = (const float*)d_in[14];
    const float* g_bn1  = (const float*)d_in[15];  const float* be_bn1 = (const float*)d_in[16];
    const float* w_sh1h = (const float*)d_in[17];  const float* b_sh1h = (const float*)d_in[18];
    const float* w_sh2h = (const float*)d_in[19];  const float* b_sh2h = (const float*)d_in[20];
    const float* w_mlp1h= (const float*)d_in[21];  const float* b_mlp1h= (const float*)d_in[22];
    const float* g_bn1h = (const float*)d_in[23];  const float* be_bn1h= (const float*)d_in[24];
    const float* w_ss   = (const float*)d_in[25];  const float* b_ss   = (const float*)d_in[26];
    const float* w_hh   = (const float*)d_in[27];  const float* b_hh   = (const float*)d_in[28];
    const float* w_mlp  = (const float*)d_in[29];  const float* b_mlp  = (const float*)d_in[30];
    const float* g_si   = (const float*)d_in[31];  const float* be_si  = (const float*)d_in[32];
    float* out = (float*)d_out;

    const int E_SH = in_sizes[1] / 2;
    const int E_SS = in_sizes[3] / 2;
    const int E_HH = in_sizes[5] / 2;
    const int B    = in_sizes[6] / N_SS;      // 20000
    const int Mp   = ((B + 127) / 128) * 128; // 20096
    const int KP1  = 416;                     // 390 padded to mult 32
    const int NP3  = 896;                     // 805 padded to mult 128

    float* w = (float*)d_ws;
    size_t off = 0;
    auto alloc = [&](size_t n) { float* p = w + off; off += (n + 3) & ~(size_t)3; return p; };

    float* adjSH   = alloc((size_t)N_SH * N_SH);
    float* adjSS   = alloc((size_t)N_SS * N_SS);
    float* adjHH   = alloc((size_t)N_HH * N_HH);
    float* cntInv  = alloc(N_SH);
    float* presInv = alloc(B);
    float* stats   = alloc(512);
    float* tmpH    = alloc((size_t)N_SH * 256);
    float* x2      = alloc((size_t)N_SH * DIM);
    float* x6      = alloc((size_t)N_SH * DIM);
    float* x9a     = alloc((size_t)N_SH * DIM);
    float* x9      = alloc((size_t)N_SH * 256);
    float* x99     = alloc((size_t)N_SH * 256);
    float* ss1     = alloc((size_t)N_SS * 256);
    float* hh1     = alloc((size_t)N_HH * 256);
    float* xhh0    = alloc((size_t)N_HH * 91);
    ushort* es_bT  = (ushort*)alloc((size_t)256 * KP1 / 2);
    ushort* wmlp2  = (ushort*)alloc((size_t)256 * 512 / 2);
    ushort* eh_b   = (ushort*)alloc((size_t)NP3 * 256 / 2);
    // region A: P_b bf16 [Mp][416] -> bufM f32 [Mp][256]   (disjoint lifetimes)
    float* regionA = alloc((size_t)Mp * 256);
    ushort* P_b    = (ushort*)regionA;
    float*  bufM   = regionA;
    // region B: e_hilo bf16 [Mp][512] -> e2_b bf16 [Mp][256] (disjoint lifetimes)
    float* regionB = alloc((size_t)Mp * 256);
    ushort* e_hilo = (ushort*)regionB;
    ushort* e2_b   = (ushort*)regionB;
    (void)ws_size; (void)n_in; (void)out_size;

    auto gemm = [&](const float* Am, const float* Bm, const float* bias, const float* rs,
                    float* C, int M, int N, int K, int act) {
        dim3 g((N + BN - 1) / BN, (M + BM - 1) / BM);
        gemm_kernel<<<g, 256, 0, stream>>>(Am, Bm, bias, rs, C, M, N, K, act);
    };
    auto mgemm = [&](const ushort* Am, const ushort* Bm, int M, int Np, int Nw, int K, int lda,
                     const float* bias, const float* rs,
                     float* oF, ushort* oB, ushort* oLo, int ldo) {
        dim3 g(Np / 128, (M + 127) / 128);
        mfma_gemm_kernel<<<g, 256, 0, stream>>>(Am, Bm, M, Nw, K, lda, bias, rs, oF, oB, oLo, ldo);
    };

    // adjacency matrices (zero then count)
    hipMemsetAsync(adjSH, 0,
                   ((size_t)N_SH * N_SH + (size_t)N_SS * N_SS + (size_t)N_HH * N_HH + 16) * sizeof(float),
                   stream);
    build_adj_kernel<<<(E_SH + 255) / 256, 256, 0, stream>>>(eiSH, E_SH, adjSH, N_SH);
    build_adj_kernel<<<(E_SS + 255) / 256, 256, 0, stream>>>(eiSS, E_SS, adjSS, N_SS);
    build_adj_kernel<<<(E_HH + 255) / 256, 256, 0, stream>>>(eiHH, E_HH, adjHH, N_HH);
    rowsum_inv_kernel<<<(N_SH + 3) / 4, 256, 0, stream>>>(adjSH, N_SH, N_SH, cntInv, 1);

    // ---- symptom branch (SH graph, mean agg) ----
    gemm(emb, w_sh1, b_sh1, nullptr, tmpH, N_SH, DIM, DIM, 0);
    gemm(adjSH, tmpH, nullptr, cntInv, x2, N_SH, DIM, N_SH, 1);
    gemm(x2, w_sh2, b_sh2, nullptr, tmpH, N_SH, DIM, DIM, 0);
    gemm(adjSH, tmpH, nullptr, cntInv, x6, N_SH, DIM, N_SH, 1);
    int nEl = N_SH * DIM;
    avg3_kernel<<<(nEl + 255) / 256, 256, 0, stream>>>(emb, x2, x6, x9a, nEl);
    gemm(x9a, w_mlp1, b_mlp1, nullptr, tmpH, N_SH, 256, DIM, 0);
    hipMemsetAsync(stats, 0, 512 * sizeof(float), stream);
    bn_stats_kernel<<<64, 256, 0, stream>>>(tmpH, N_SH, stats);
    bn_apply_kernel<<<(N_SH * 256 + 255) / 256, 256, 0, stream>>>(tmpH, stats, g_bn1, be_bn1, N_SH, x9, 1);

    // ---- herb branch ----
    gemm(emb, w_sh1h, b_sh1h, nullptr, tmpH, N_SH, DIM, DIM, 0);
    gemm(adjSH, tmpH, nullptr, cntInv, x2, N_SH, DIM, N_SH, 1);
    gemm(x2, w_sh2h, b_sh2h, nullptr, tmpH, N_SH, DIM, DIM, 0);
    gemm(adjSH, tmpH, nullptr, cntInv, x6, N_SH, DIM, N_SH, 1);
    avg3_kernel<<<(nEl + 255) / 256, 256, 0, stream>>>(emb, x2, x6, x9a, nEl);
    gemm(x9a, w_mlp1h, b_mlp1h, nullptr, tmpH, N_SH, 256, DIM, 0);
    hipMemsetAsync(stats, 0, 512 * sizeof(float), stream);
    bn_stats_kernel<<<64, 256, 0, stream>>>(tmpH, N_SH, stats);
    bn_apply_kernel<<<(N_SH * 256 + 255) / 256, 256, 0, stream>>>(tmpH, stats, g_bn1h, be_bn1h, N_SH, x99, 1);

    // ---- SS graph (add agg) ----
    gemm(emb, w_ss, b_ss, nullptr, tmpH, N_SS, 256, DIM, 0);
    gemm(adjSS, tmpH, nullptr, nullptr, ss1, N_SS, 256, N_SS, 1);

    // ---- HH graph ----
    concat_hh_kernel<<<(N_HH * 91 + 255) / 256, 256, 0, stream>>>(emb, kg, xhh0);
    gemm(xhh0, w_hh, b_hh, nullptr, tmpH, N_HH, 256, 91, 0);
    gemm(adjHH, tmpH, nullptr, nullptr, hh1, N_HH, 256, N_HH, 1);

    // ---- prepare bf16 operands ----
    make_esbt_kernel<<<(256 * KP1 + 255) / 256, 256, 0, stream>>>(x9, ss1, es_bT, KP1);
    make_wmlp2_kernel<<<(256 * 512 + 255) / 256, 256, 0, stream>>>(w_mlp, wmlp2);
    make_ehb_kernel<<<(NP3 * 256 + 255) / 256, 256, 0, stream>>>(x99, hh1, eh_b, NP3);
    {
        long long n = (long long)B * KP1;
        cvt_pad_kernel<<<(unsigned)((n + 255) / 256), 256, 0, stream>>>(P, B, N_SS, P_b, KP1);
    }
    rowsum_inv_kernel<<<(B + 3) / 4, 256, 0, stream>>>(P, B, N_SS, presInv, 0);

    // ---- prescription path (bf16 MFMA) ----
    // C1: e = (P @ es) * presInv, emitted as hi/lo bf16 pair into [Mp][512]
    mgemm(P_b, es_bT, B, 256, 256, KP1, KP1, nullptr, presInv,
          nullptr, e_hilo, e_hilo + 256, 512);
    // C2: bufM = (e_hi + e_lo) @ w_mlp + b_mlp   (K=512 against duplicated w^T)
    mgemm(e_hilo, wmlp2, B, 256, 256, 512, 512, b_mlp, nullptr,
          bufM, nullptr, nullptr, 256);
    // BN + relu -> bf16
    hipMemsetAsync(stats, 0, 512 * sizeof(float), stream);
    bn_stats_kernel<<<256, 256, 0, stream>>>(bufM, B, stats);
    bn_apply_bf16_kernel<<<(B * 256 + 255) / 256, 256, 0, stream>>>(bufM, stats, g_si, be_si, B, e2_b);
    // C3: out = e2 @ eh^T
    mgemm(e2_b, eh_b, B, NP3, N_HH, 256, 256, nullptr, nullptr,
          out, nullptr, nullptr, N_HH);
}

// Round 4
// 446.081 us; speedup vs baseline: 3.1749x; 2.4016x over previous
//
#include <hip/hip_runtime.h>
#include <cstddef>
#include <cstdint>

#define N_SH 1195
#define N_SS 390
#define N_HH 805
#define DIM  64

typedef __bf16 bf16_t;
typedef bf16_t bf16x4v __attribute__((ext_vector_type(4)));
typedef bf16_t bf16x8v __attribute__((ext_vector_type(8)));
typedef float f32x4 __attribute__((ext_vector_type(4)));

__device__ inline ushort f2bf(float f) {
    union { float f; uint32_t u; } c; c.f = f;
    uint32_t u = c.u;
    u += 0x7FFFu + ((u >> 16) & 1u);
    return (ushort)(u >> 16);
}

// ---------------- adjacency build (counts; exact & order-independent) -------
__global__ void build_adj_kernel(const int* __restrict__ ei, int E,
                                 float* __restrict__ A, int N) {
    int i = blockIdx.x * blockDim.x + threadIdx.x;
    if (i < E) {
        int src = ei[i];
        int dst = ei[E + i];
        atomicAdd(&A[(size_t)dst * N + src], 1.0f);
    }
}

__global__ void rowsum_inv_kernel(const float* __restrict__ X, int M, int K,
                                  float* __restrict__ inv, int use_max1) {
    int row  = blockIdx.x * (blockDim.x / 64) + (threadIdx.x / 64);
    int lane = threadIdx.x & 63;
    if (row >= M) return;
    const float* p = X + (size_t)row * K;
    float s = 0.f;
    for (int c = lane; c < K; c += 64) s += p[c];
    for (int off = 32; off > 0; off >>= 1) s += __shfl_down(s, off);
    if (lane == 0) {
        float d = use_max1 ? fmaxf(s, 1.0f) : s;
        inv[row] = 1.0f / d;
    }
}

// ---------------- fp32 GEMM (small dense layers) ----------------------------
#define BM 64
#define BN 64
#define BK 16

__global__ __launch_bounds__(256) void gemm_kernel(
    const float* __restrict__ A, const float* __restrict__ B,
    const float* __restrict__ bias, const float* __restrict__ rowScale,
    float* __restrict__ C, int M, int N, int K, int act)
{
    __shared__ float As[BK][BM + 4];
    __shared__ float Bs[BK][BN];
    const int tid  = threadIdx.x;
    const int row0 = blockIdx.y * BM;
    const int col0 = blockIdx.x * BN;
    const int tr  = (tid >> 4) << 2;
    const int tc  = (tid & 15) << 2;
    const int lar = tid >> 2;
    const int lac = (tid & 3) << 2;
    const int lbr = tid >> 4;
    const int lbc = (tid & 15) << 2;

    float acc[4][4] = {{0.f}};

    for (int k0 = 0; k0 < K; k0 += BK) {
        const int gr = row0 + lar;
        const float* Ap = A + (size_t)gr * K + k0 + lac;
        #pragma unroll
        for (int i = 0; i < 4; ++i) {
            int gk = k0 + lac + i;
            As[lac + i][lar] = (gr < M && gk < K) ? Ap[i] : 0.f;
        }
        const int gk = k0 + lbr;
        const float* Bp = B + (size_t)gk * N + col0 + lbc;
        #pragma unroll
        for (int i = 0; i < 4; ++i) {
            int gc = col0 + lbc + i;
            Bs[lbr][lbc + i] = (gk < K && gc < N) ? Bp[i] : 0.f;
        }
        __syncthreads();
        #pragma unroll
        for (int kk = 0; kk < BK; ++kk) {
            float4 a = *reinterpret_cast<const float4*>(&As[kk][tr]);
            float4 b = *reinterpret_cast<const float4*>(&Bs[kk][tc]);
            acc[0][0] += a.x * b.x; acc[0][1] += a.x * b.y; acc[0][2] += a.x * b.z; acc[0][3] += a.x * b.w;
            acc[1][0] += a.y * b.x; acc[1][1] += a.y * b.y; acc[1][2] += a.y * b.z; acc[1][3] += a.y * b.w;
            acc[2][0] += a.z * b.x; acc[2][1] += a.z * b.y; acc[2][2] += a.z * b.z; acc[2][3] += a.z * b.w;
            acc[3][0] += a.w * b.x; acc[3][1] += a.w * b.y; acc[3][2] += a.w * b.z; acc[3][3] += a.w * b.w;
        }
        __syncthreads();
    }

    #pragma unroll
    for (int i = 0; i < 4; ++i) {
        int gr = row0 + tr + i;
        if (gr >= M) continue;
        float rs = rowScale ? rowScale[gr] : 1.0f;
        #pragma unroll
        for (int j = 0; j < 4; ++j) {
            int gc = col0 + tc + j;
            if (gc >= N) continue;
            float v = acc[i][j];
            if (bias) v += bias[gc];
            v *= rs;
            if (act == 1) v = tanhf(v);
            C[(size_t)gr * N + gc] = v;
        }
    }
}

// ---------------- bf16 MFMA GEMM: 128x128 tile, BK=32, 4 waves --------------
#define LDT 40

__global__ __launch_bounds__(256) void mfma_gemm_kernel(
    const ushort* __restrict__ A, const ushort* __restrict__ Bt,
    int M, int Nw, int K, int lda,
    const float* __restrict__ bias, const float* __restrict__ rowScale,
    float* __restrict__ outF, ushort* __restrict__ outB, ushort* __restrict__ outLo,
    int ldo)
{
    __shared__ __align__(16) ushort As[128 * LDT];
    __shared__ __align__(16) ushort Bs[128 * LDT];
    const int tid  = threadIdx.x;
    const int row0 = blockIdx.y * 128;
    const int col0 = blockIdx.x * 128;
    const int wid  = tid >> 6, lane = tid & 63;
    const int wr = wid >> 1, wc = wid & 1;
    const int l15 = lane & 15, lg = lane >> 4;
    const int kg = lg * 4;
    const int sr = tid >> 2;
    const int sc = (tid & 3) * 8;

    f32x4 acc[4][4];
    #pragma unroll
    for (int m = 0; m < 4; ++m)
        #pragma unroll
        for (int n = 0; n < 4; ++n) acc[m][n] = (f32x4)0.f;

    for (int k0 = 0; k0 < K; k0 += 32) {
        const ushort* ga0 = A  + (size_t)(row0 + sr)      * lda + k0 + sc;
        const ushort* ga1 = A  + (size_t)(row0 + sr + 64) * lda + k0 + sc;
        const ushort* gb0 = Bt + (size_t)(col0 + sr)      * lda + k0 + sc;
        const ushort* gb1 = Bt + (size_t)(col0 + sr + 64) * lda + k0 + sc;
        *reinterpret_cast<uint4*>(&As[sr * LDT + sc])        = *reinterpret_cast<const uint4*>(ga0);
        *reinterpret_cast<uint4*>(&As[(sr + 64) * LDT + sc]) = *reinterpret_cast<const uint4*>(ga1);
        *reinterpret_cast<uint4*>(&Bs[sr * LDT + sc])        = *reinterpret_cast<const uint4*>(gb0);
        *reinterpret_cast<uint4*>(&Bs[(sr + 64) * LDT + sc]) = *reinterpret_cast<const uint4*>(gb1);
        __syncthreads();

        bf16x8v af[4], bfr[4];
        #pragma unroll
        for (int m = 0; m < 4; ++m) {
            int ar = wr * 64 + m * 16 + l15;
            bf16x4v lo = *reinterpret_cast<const bf16x4v*>(&As[ar * LDT + kg]);
            bf16x4v hi = *reinterpret_cast<const bf16x4v*>(&As[ar * LDT + kg + 16]);
            af[m] = __builtin_shufflevector(lo, hi, 0, 1, 2, 3, 4, 5, 6, 7);
        }
        #pragma unroll
        for (int n = 0; n < 4; ++n) {
            int br = wc * 64 + n * 16 + l15;
            bf16x4v lo = *reinterpret_cast<const bf16x4v*>(&Bs[br * LDT + kg]);
            bf16x4v hi = *reinterpret_cast<const bf16x4v*>(&Bs[br * LDT + kg + 16]);
            bfr[n] = __builtin_shufflevector(lo, hi, 0, 1, 2, 3, 4, 5, 6, 7);
        }
        #pragma unroll
        for (int m = 0; m < 4; ++m)
            #pragma unroll
            for (int n = 0; n < 4; ++n)
                acc[m][n] = __builtin_amdgcn_mfma_f32_16x16x32_bf16(af[m], bfr[n], acc[m][n], 0, 0, 0);
        __syncthreads();
    }

    #pragma unroll
    for (int m = 0; m < 4; ++m) {
        int grow_base = row0 + wr * 64 + m * 16 + kg;
        #pragma unroll
        for (int j = 0; j < 4; ++j) {
            int grow = grow_base + j;
            if (grow >= M) continue;
            float rs = rowScale ? rowScale[grow] : 1.0f;
            #pragma unroll
            for (int n = 0; n < 4; ++n) {
                int gcol = col0 + wc * 64 + n * 16 + l15;
                if (gcol >= Nw) continue;
                float v = acc[m][n][j];
                if (bias) v += bias[gcol];
                v *= rs;
                if (outB) {
                    ushort h = f2bf(v);
                    outB[(size_t)grow * ldo + gcol] = h;
                    if (outLo) {
                        float hv = __uint_as_float(((uint32_t)h) << 16);
                        outLo[(size_t)grow * ldo + gcol] = f2bf(v - hv);
                    }
                } else {
                    outF[(size_t)grow * ldo + gcol] = v;
                }
            }
        }
    }
}

// ---------------- split-K MFMA: partials (f32), grid.z = K-chunk ------------
__global__ __launch_bounds__(256) void mfma_splitk_kernel(
    const ushort* __restrict__ A, const ushort* __restrict__ Bt,
    int M, int K, int lda, int kChunk, int Ntot,
    float* __restrict__ part)
{
    __shared__ __align__(16) ushort As[128 * LDT];
    __shared__ __align__(16) ushort Bs[128 * LDT];
    const int tid  = threadIdx.x;
    const int row0 = blockIdx.y * 128;
    const int col0 = blockIdx.x * 128;
    const int wid  = tid >> 6, lane = tid & 63;
    const int wr = wid >> 1, wc = wid & 1;
    const int l15 = lane & 15, lg = lane >> 4;
    const int kg = lg * 4;
    const int sr = tid >> 2;
    const int sc = (tid & 3) * 8;

    const int k0s = blockIdx.z * kChunk;
    const int k0e = (k0s + kChunk < K) ? k0s + kChunk : K;

    f32x4 acc[4][4];
    #pragma unroll
    for (int m = 0; m < 4; ++m)
        #pragma unroll
        for (int n = 0; n < 4; ++n) acc[m][n] = (f32x4)0.f;

    for (int k0 = k0s; k0 < k0e; k0 += 32) {
        const ushort* ga0 = A  + (size_t)(row0 + sr)      * lda + k0 + sc;
        const ushort* ga1 = A  + (size_t)(row0 + sr + 64) * lda + k0 + sc;
        const ushort* gb0 = Bt + (size_t)(col0 + sr)      * lda + k0 + sc;
        const ushort* gb1 = Bt + (size_t)(col0 + sr + 64) * lda + k0 + sc;
        *reinterpret_cast<uint4*>(&As[sr * LDT + sc])        = *reinterpret_cast<const uint4*>(ga0);
        *reinterpret_cast<uint4*>(&As[(sr + 64) * LDT + sc]) = *reinterpret_cast<const uint4*>(ga1);
        *reinterpret_cast<uint4*>(&Bs[sr * LDT + sc])        = *reinterpret_cast<const uint4*>(gb0);
        *reinterpret_cast<uint4*>(&Bs[(sr + 64) * LDT + sc]) = *reinterpret_cast<const uint4*>(gb1);
        __syncthreads();

        bf16x8v af[4], bfr[4];
        #pragma unroll
        for (int m = 0; m < 4; ++m) {
            int ar = wr * 64 + m * 16 + l15;
            bf16x4v lo = *reinterpret_cast<const bf16x4v*>(&As[ar * LDT + kg]);
            bf16x4v hi = *reinterpret_cast<const bf16x4v*>(&As[ar * LDT + kg + 16]);
            af[m] = __builtin_shufflevector(lo, hi, 0, 1, 2, 3, 4, 5, 6, 7);
        }
        #pragma unroll
        for (int n = 0; n < 4; ++n) {
            int br = wc * 64 + n * 16 + l15;
            bf16x4v lo = *reinterpret_cast<const bf16x4v*>(&Bs[br * LDT + kg]);
            bf16x4v hi = *reinterpret_cast<const bf16x4v*>(&Bs[br * LDT + kg + 16]);
            bfr[n] = __builtin_shufflevector(lo, hi, 0, 1, 2, 3, 4, 5, 6, 7);
        }
        #pragma unroll
        for (int m = 0; m < 4; ++m)
            #pragma unroll
            for (int n = 0; n < 4; ++n)
                acc[m][n] = __builtin_amdgcn_mfma_f32_16x16x32_bf16(af[m], bfr[n], acc[m][n], 0, 0, 0);
        __syncthreads();
    }

    float* pslab = part + (size_t)blockIdx.z * M * Ntot;
    #pragma unroll
    for (int m = 0; m < 4; ++m) {
        int grow_base = row0 + wr * 64 + m * 16 + kg;
        #pragma unroll
        for (int j = 0; j < 4; ++j) {
            int grow = grow_base + j;
            if (grow >= M) continue;
            #pragma unroll
            for (int n = 0; n < 4; ++n) {
                int gcol = col0 + wc * 64 + n * 16 + l15;
                pslab[(size_t)grow * Ntot + gcol] = acc[m][n][j];
            }
        }
    }
}

// out[r][c] = tanh( (sum_z part[z][r][c]) * (rs ? rs[r] : 1) )
__global__ void reduce_tanh_kernel(const float* __restrict__ part, int S, int M, int N,
                                   const float* __restrict__ rs, float* __restrict__ out) {
    int i = blockIdx.x * blockDim.x + threadIdx.x;
    if (i >= M * N) return;
    int r = i / N;
    float s = 0.f;
    for (int z = 0; z < S; ++z) s += part[(size_t)z * M * N + i];
    if (rs) s *= rs[r];
    out[i] = tanhf(s);
}

// ---------------- conversion / fusion helpers -------------------------------
// f32 [R][C] -> bf16 [Rp][Cp], zero-padded
__global__ void cvt_pad2_kernel(const float* __restrict__ in, int R, int C,
                                ushort* __restrict__ out, int Rp, int Cp) {
    int i = blockIdx.x * blockDim.x + threadIdx.x;
    if (i >= Rp * Cp) return;
    int r = i / Cp, c = i % Cp;
    float v = (r < R && c < C) ? in[(size_t)r * C + c] : 0.f;
    out[i] = f2bf(v);
}

// f32 [R][Cp-pad...] -> bf16 (row-pad only, for P)
__global__ void cvt_pad_kernel(const float* __restrict__ in, int R, int C,
                               ushort* __restrict__ out, int Cp) {
    long long i = (long long)blockIdx.x * blockDim.x + threadIdx.x;
    long long n = (long long)R * Cp;
    if (i >= n) return;
    int r = (int)(i / Cp), c = (int)(i % Cp);
    float v = (c < C) ? in[(size_t)r * C + c] : 0.f;
    out[i] = f2bf(v);
}

// transpose+convert: in [K][N] f32 (ld = ldin) -> out [N][Kp] bf16, zero pad k>=K
__global__ void transpose_cvt_kernel(const float* __restrict__ in, int K, int N, int ldin,
                                     ushort* __restrict__ out, int Kp) {
    int i = blockIdx.x * blockDim.x + threadIdx.x;
    if (i >= N * Kp) return;
    int n = i / Kp, k = i % Kp;
    float v = (k < K) ? in[(size_t)k * ldin + n] : 0.f;
    out[i] = f2bf(v);
}

// concatenated / block-diagonal weight assembly
__global__ void make_cat_weights_kernel(
    const float* __restrict__ w_sh1, const float* __restrict__ w_sh1h,
    const float* __restrict__ b_sh1, const float* __restrict__ b_sh1h,
    const float* __restrict__ w_sh2, const float* __restrict__ w_sh2h,
    const float* __restrict__ b_sh2, const float* __restrict__ b_sh2h,
    const float* __restrict__ w_mlp1, const float* __restrict__ w_mlp1h,
    const float* __restrict__ b_mlp1, const float* __restrict__ b_mlp1h,
    float* __restrict__ W1cat, float* __restrict__ b1cat,
    float* __restrict__ W2bd,  float* __restrict__ b2cat,
    float* __restrict__ WMbd,  float* __restrict__ bMcat)
{
    int i = blockIdx.x * blockDim.x + threadIdx.x;
    if (i < 64 * 128) {
        int k = i >> 7, j = i & 127;
        W1cat[i] = (j < 64) ? w_sh1[k * 64 + j] : w_sh1h[k * 64 + (j - 64)];
        return;
    }
    i -= 64 * 128;
    if (i < 128) { b1cat[i] = (i < 64) ? b_sh1[i] : b_sh1h[i - 64]; return; }
    i -= 128;
    if (i < 128 * 128) {
        int k = i >> 7, j = i & 127;
        float v = 0.f;
        if (k < 64 && j < 64) v = w_sh2[k * 64 + j];
        else if (k >= 64 && j >= 64) v = w_sh2h[(k - 64) * 64 + (j - 64)];
        W2bd[i] = v;
        return;
    }
    i -= 128 * 128;
    if (i < 128) { b2cat[i] = (i < 64) ? b_sh2[i] : b_sh2h[i - 64]; return; }
    i -= 128;
    if (i < 128 * 512) {
        int k = i >> 9, j = i & 511;
        float v = 0.f;
        if (j < 256) { if (k < 64) v = w_mlp1[k * 256 + j]; }
        else         { if (k >= 64) v = w_mlp1h[(k - 64) * 256 + (j - 256)]; }
        WMbd[i] = v;
        return;
    }
    i -= 128 * 512;
    if (i < 512) { bMcat[i] = (i < 256) ? b_mlp1[i] : b_mlp1h[i - 256]; }
}

// x9a2[r][j] = (emb[r][j&63] + x2cat[r][j] + x6cat[r][j]) / 3
__global__ void avg3cat_kernel(const float* __restrict__ emb, const float* __restrict__ x2cat,
                               const float* __restrict__ x6cat, float* __restrict__ o) {
    int i = blockIdx.x * blockDim.x + threadIdx.x;
    if (i >= N_SH * 128) return;
    int r = i >> 7, j = i & 127;
    o[i] = (emb[r * 64 + (j & 63)] + x2cat[i] + x6cat[i]) * (1.0f / 3.0f);
}

__global__ void concat_hh_kernel(const float* __restrict__ emb, const float* __restrict__ kg,
                                 float* __restrict__ out) {
    int i = blockIdx.x * blockDim.x + threadIdx.x;
    const int n = N_HH * 91;
    if (i >= n) return;
    int r = i / 91, c = i % 91;
    out[i] = (c < DIM) ? emb[r * DIM + c] : kg[r * 27 + (c - DIM)];
}

// es^T bf16 [256][Kp]: es = x9cat[:,0:256][:N_SS] + ss1
__global__ void make_esbt_kernel(const float* __restrict__ x9cat, const float* __restrict__ ss1,
                                 ushort* __restrict__ out, int Kp) {
    int i = blockIdx.x * blockDim.x + threadIdx.x;
    if (i >= 256 * Kp) return;
    int n = i / Kp, k = i % Kp;
    float v = (k < N_SS) ? (x9cat[(size_t)k * 512 + n] + ss1[(size_t)k * 256 + n]) : 0.f;
    out[i] = f2bf(v);
}

// w_mlp^T duplicated: [256][512]
__global__ void make_wmlp2_kernel(const float* __restrict__ wm, ushort* __restrict__ out) {
    int i = blockIdx.x * blockDim.x + threadIdx.x;
    if (i >= 256 * 512) return;
    int n = i >> 9, k = i & 511;
    out[i] = f2bf(wm[(size_t)(k & 255) * 256 + n]);
}

// eh bf16 [Rp][256]: eh = x9cat[:,256:512][N_SS:] + hh1, row-padded
__global__ void make_ehb_kernel(const float* __restrict__ x9cat, const float* __restrict__ hh1,
                                ushort* __restrict__ out, int Rp) {
    int i = blockIdx.x * blockDim.x + threadIdx.x;
    if (i >= Rp * 256) return;
    int r = i >> 8, c = i & 255;
    float v = (r < N_HH) ? (x9cat[(size_t)(N_SS + r) * 512 + 256 + c] + hh1[(size_t)r * 256 + c]) : 0.f;
    out[i] = f2bf(v);
}

// ---------------- BatchNorm -------------------------------------------------
// dual-branch stats over 512 cols
__global__ void bn_stats_cat_kernel(const float* __restrict__ X, int M,
                                    float* __restrict__ stats) {
    int j = threadIdx.x;  // 512
    float s = 0.f, ss = 0.f;
    for (int r = blockIdx.x; r < M; r += gridDim.x) {
        float v = X[(size_t)r * 512 + j];
        s += v; ss += v * v;
    }
    atomicAdd(&stats[j], s);
    atomicAdd(&stats[512 + j], ss);
}

__global__ void bn_apply_cat_kernel(const float* __restrict__ X, const float* __restrict__ stats,
                                    const float* __restrict__ g1, const float* __restrict__ be1,
                                    const float* __restrict__ g2, const float* __restrict__ be2,
                                    int M, float* __restrict__ out) {
    int i = blockIdx.x * blockDim.x + threadIdx.x;
    if (i >= M * 512) return;
    int j = i & 511;
    float invM = 1.0f / (float)M;
    float mean = stats[j] * invM;
    float var  = fmaxf(stats[512 + j] * invM - mean * mean, 0.f);
    float ga = (j < 256) ? g1[j]  : g2[j - 256];
    float bb = (j < 256) ? be1[j] : be2[j - 256];
    float y = (X[i] - mean) * rsqrtf(var + 1e-5f) * ga + bb;
    out[i] = tanhf(y);
}

// single 256-col stats (prescription path)
__global__ void bn_stats_kernel(const float* __restrict__ X, int M,
                                float* __restrict__ stats) {
    int j = threadIdx.x;
    float s = 0.f, ss = 0.f;
    for (int r = blockIdx.x; r < M; r += gridDim.x) {
        float v = X[(size_t)r * 256 + j];
        s += v; ss += v * v;
    }
    atomicAdd(&stats[j], s);
    atomicAdd(&stats[256 + j], ss);
}

__global__ void bn_apply_bf16_kernel(const float* __restrict__ X, const float* __restrict__ stats,
                                     const float* __restrict__ g, const float* __restrict__ be,
                                     int M, ushort* __restrict__ out) {
    long long i = (long long)blockIdx.x * blockDim.x + threadIdx.x;
    long long n = (long long)M * 256;
    if (i >= n) return;
    int j = (int)(i & 255);
    float invM = 1.0f / (float)M;
    float mean = stats[j] * invM;
    float var  = fmaxf(stats[256 + j] * invM - mean * mean, 0.f);
    float y = (X[i] - mean) * rsqrtf(var + 1e-5f) * g[j] + be[j];
    out[i] = f2bf(fmaxf(y, 0.f));
}

// ---------------- driver -----------------------------------------------------
extern "C" void kernel_launch(void* const* d_in, const int* in_sizes, int n_in,
                              void* d_out, int out_size, void* d_ws, size_t ws_size,
                              hipStream_t stream) {
    const int*   eiSH = (const int*)d_in[1];
    const int*   eiSS = (const int*)d_in[3];
    const int*   eiHH = (const int*)d_in[5];
    const float* P    = (const float*)d_in[6];
    const float* kg   = (const float*)d_in[7];
    const float* emb  = (const float*)d_in[8];
    const float* w_sh1  = (const float*)d_in[9];   const float* b_sh1  = (const float*)d_in[10];
    const float* w_sh2  = (const float*)d_in[11];  const float* b_sh2  = (const float*)d_in[12];
    const float* w_mlp1 = (const float*)d_in[13];  const float* b_mlp1 = (const float*)d_in[14];
    const float* g_bn1  = (const float*)d_in[15];  const float* be_bn1 = (const float*)d_in[16];
    const float* w_sh1h = (const float*)d_in[17];  const float* b_sh1h = (const float*)d_in[18];
    const float* w_sh2h = (const float*)d_in[19];  const float* b_sh2h = (const float*)d_in[20];
    const float* w_mlp1h= (const float*)d_in[21];  const float* b_mlp1h= (const float*)d_in[22];
    const float* g_bn1h = (const float*)d_in[23];  const float* be_bn1h= (const float*)d_in[24];
    const float* w_ss   = (const float*)d_in[25];  const float* b_ss   = (const float*)d_in[26];
    const float* w_hh   = (const float*)d_in[27];  const float* b_hh   = (const float*)d_in[28];
    const float* w_mlp  = (const float*)d_in[29];  const float* b_mlp  = (const float*)d_in[30];
    const float* g_si   = (const float*)d_in[31];  const float* be_si  = (const float*)d_in[32];
    float* out = (float*)d_out;

    const int E_SH = in_sizes[1] / 2;
    const int E_SS = in_sizes[3] / 2;
    const int E_HH = in_sizes[5] / 2;
    const int B    = in_sizes[6] / N_SS;      // 20000
    const int Mp   = ((B + 127) / 128) * 128; // 20096
    const int KP1  = 416;                     // 390 -> mult 32
    const int NP3  = 896;                     // 805 -> mult 128
    const int KSH  = 1216;                    // 1195 -> mult 32
    const int KHH  = 832;                     // 805 -> mult 32

    float* w = (float*)d_ws;
    size_t off = 0;
    auto alloc = [&](size_t n) { float* p = w + off; off += (n + 3) & ~(size_t)3; return p; };

    // -- persistent small buffers --
    float* cntInv  = alloc(N_SH);
    float* presInv = alloc(B);
    float* stats   = alloc(1024);
    float* W1cat   = alloc(64 * 128);
    float* b1cat   = alloc(128);
    float* W2bd    = alloc(128 * 128);
    float* b2cat   = alloc(128);
    float* WMbd    = alloc(128 * 512);
    float* bMcat   = alloc(512);
    ushort* adjb   = (ushort*)alloc((size_t)1280 * KSH / 2);
    ushort* adjSSb = (ushort*)alloc((size_t)512 * KP1 / 2);
    ushort* adjHHb = (ushort*)alloc((size_t)896 * KHH / 2);
    float* tmpL    = alloc((size_t)N_SH * 128);
    ushort* HT     = (ushort*)alloc((size_t)128 * KSH / 2);   // reused layer1/2
    float* x2cat   = alloc((size_t)N_SH * 128);
    float* x6cat   = alloc((size_t)N_SH * 128);
    float* x9a2    = alloc((size_t)N_SH * 128);
    float* tmpBN   = alloc((size_t)N_SH * 512);               // also SS/HH lin out
    float* x9cat   = alloc((size_t)N_SH * 512);
    float* ss1     = alloc((size_t)N_SS * 256);
    float* hh1     = alloc((size_t)N_HH * 256);
    float* xhh0    = alloc((size_t)N_HH * 91);
    ushort* HSST   = (ushort*)alloc((size_t)256 * KP1 / 2);
    ushort* HHHT   = (ushort*)alloc((size_t)256 * KHH / 2);
    ushort* es_bT  = (ushort*)alloc((size_t)256 * KP1 / 2);
    ushort* wmlp2  = (ushort*)alloc((size_t)256 * 512 / 2);
    ushort* eh_b   = (ushort*)alloc((size_t)NP3 * 256 / 2);
    // region A: f32 adjacency (early) -> P_b bf16 [Mp][416] -> bufM f32 [Mp][256]
    float* regionA = alloc((size_t)Mp * 256);
    float* adjSH   = regionA;
    float* adjSS   = regionA + (size_t)N_SH * N_SH;
    float* adjHH   = adjSS + (size_t)N_SS * N_SS;
    ushort* P_b    = (ushort*)regionA;
    float*  bufM   = regionA;
    // region B: split-K partials (early) -> e_hilo bf16 [Mp][512] -> e2_b
    float* regionB = alloc((size_t)Mp * 256);
    float*  partials = regionB;
    ushort* e_hilo = (ushort*)regionB;
    ushort* e2_b   = (ushort*)regionB;
    (void)ws_size; (void)n_in; (void)out_size;

    auto gemm = [&](const float* Am, const float* Bm, const float* bias, const float* rs,
                    float* C, int M, int N, int K, int act) {
        dim3 g((N + BN - 1) / BN, (M + BM - 1) / BM);
        gemm_kernel<<<g, 256, 0, stream>>>(Am, Bm, bias, rs, C, M, N, K, act);
    };
    auto mgemm = [&](const ushort* Am, const ushort* Bm, int M, int Np, int Nw, int K, int lda,
                     const float* bias, const float* rs,
                     float* oF, ushort* oB, ushort* oLo, int ldo) {
        dim3 g(Np / 128, (M + 127) / 128);
        mfma_gemm_kernel<<<g, 256, 0, stream>>>(Am, Bm, M, Nw, K, lda, bias, rs, oF, oB, oLo, ldo);
    };
    auto splitk = [&](const ushort* Am, const ushort* Bm, int M, int Mtiles, int K, int lda,
                      int Ntot, int S, const float* rs, float* outp) {
        dim3 g(Ntot / 128, Mtiles, S);
        mfma_splitk_kernel<<<g, 256, 0, stream>>>(Am, Bm, M, K, lda, 128, Ntot, partials);
        reduce_tanh_kernel<<<(M * Ntot + 255) / 256, 256, 0, stream>>>(partials, S, M, Ntot, rs, outp);
    };

    // ---- adjacency (f32 counts in regionA, then bf16 copies) ----
    hipMemsetAsync(regionA, 0,
                   ((size_t)N_SH * N_SH + (size_t)N_SS * N_SS + (size_t)N_HH * N_HH + 16) * sizeof(float),
                   stream);
    build_adj_kernel<<<(E_SH + 255) / 256, 256, 0, stream>>>(eiSH, E_SH, adjSH, N_SH);
    build_adj_kernel<<<(E_SS + 255) / 256, 256, 0, stream>>>(eiSS, E_SS, adjSS, N_SS);
    build_adj_kernel<<<(E_HH + 255) / 256, 256, 0, stream>>>(eiHH, E_HH, adjHH, N_HH);
    rowsum_inv_kernel<<<(N_SH + 3) / 4, 256, 0, stream>>>(adjSH, N_SH, N_SH, cntInv, 1);
    cvt_pad2_kernel<<<(1280 * KSH + 255) / 256, 256, 0, stream>>>(adjSH, N_SH, N_SH, adjb, 1280, KSH);
    cvt_pad2_kernel<<<(512 * KP1 + 255) / 256, 256, 0, stream>>>(adjSS, N_SS, N_SS, adjSSb, 512, KP1);
    cvt_pad2_kernel<<<(896 * KHH + 255) / 256, 256, 0, stream>>>(adjHH, N_HH, N_HH, adjHHb, 896, KHH);

    make_cat_weights_kernel<<<(90880 + 255) / 256, 256, 0, stream>>>(
        w_sh1, w_sh1h, b_sh1, b_sh1h, w_sh2, w_sh2h, b_sh2, b_sh2h,
        w_mlp1, w_mlp1h, b_mlp1, b_mlp1h,
        W1cat, b1cat, W2bd, b2cat, WMbd, bMcat);

    // ---- SH layer 1 (both branches, N=128) ----
    gemm(emb, W1cat, b1cat, nullptr, tmpL, N_SH, 128, 64, 0);
    transpose_cvt_kernel<<<(128 * KSH + 255) / 256, 256, 0, stream>>>(tmpL, N_SH, 128, 128, HT, KSH);
    splitk(adjb, HT, N_SH, 10, KSH, KSH, 128, 10, cntInv, x2cat);
    // ---- SH layer 2 ----
    gemm(x2cat, W2bd, b2cat, nullptr, tmpL, N_SH, 128, 128, 0);
    transpose_cvt_kernel<<<(128 * KSH + 255) / 256, 256, 0, stream>>>(tmpL, N_SH, 128, 128, HT, KSH);
    splitk(adjb, HT, N_SH, 10, KSH, KSH, 128, 10, cntInv, x6cat);
    // ---- x9a (both branches) + MLP + dual BN ----
    avg3cat_kernel<<<(N_SH * 128 + 255) / 256, 256, 0, stream>>>(emb, x2cat, x6cat, x9a2);
    gemm(x9a2, WMbd, bMcat, nullptr, tmpBN, N_SH, 512, 128, 0);
    hipMemsetAsync(stats, 0, 1024 * sizeof(float), stream);
    bn_stats_cat_kernel<<<64, 512, 0, stream>>>(tmpBN, N_SH, stats);
    bn_apply_cat_kernel<<<(N_SH * 512 + 255) / 256, 256, 0, stream>>>(
        tmpBN, stats, g_bn1, be_bn1, g_bn1h, be_bn1h, N_SH, x9cat);

    // ---- SS graph ----
    gemm(emb, w_ss, b_ss, nullptr, tmpBN, N_SS, 256, 64, 0);
    transpose_cvt_kernel<<<(256 * KP1 + 255) / 256, 256, 0, stream>>>(tmpBN, N_SS, 256, 256, HSST, KP1);
    splitk(adjSSb, HSST, N_SS, 4, KP1, KP1, 256, 4, nullptr, ss1);

    // ---- HH graph ----
    concat_hh_kernel<<<(N_HH * 91 + 255) / 256, 256, 0, stream>>>(emb, kg, xhh0);
    gemm(xhh0, w_hh, b_hh, nullptr, tmpBN, N_HH, 256, 91, 0);
    transpose_cvt_kernel<<<(256 * KHH + 255) / 256, 256, 0, stream>>>(tmpBN, N_HH, 256, 256, HHHT, KHH);
    splitk(adjHHb, HHHT, N_HH, 7, KHH, KHH, 256, 7, nullptr, hh1);

    // ---- prepare bf16 operands for prescription path ----
    make_esbt_kernel<<<(256 * KP1 + 255) / 256, 256, 0, stream>>>(x9cat, ss1, es_bT, KP1);
    make_wmlp2_kernel<<<(256 * 512 + 255) / 256, 256, 0, stream>>>(w_mlp, wmlp2);
    make_ehb_kernel<<<(NP3 * 256 + 255) / 256, 256, 0, stream>>>(x9cat, hh1, eh_b, NP3);
    {
        long long n = (long long)B * KP1;
        cvt_pad_kernel<<<(unsigned)((n + 255) / 256), 256, 0, stream>>>(P, B, N_SS, P_b, KP1);
    }
    rowsum_inv_kernel<<<(B + 3) / 4, 256, 0, stream>>>(P, B, N_SS, presInv, 0);

    // ---- prescription path (bf16 MFMA) ----
    mgemm(P_b, es_bT, B, 256, 256, KP1, KP1, nullptr, presInv,
          nullptr, e_hilo, e_hilo + 256, 512);
    mgemm(e_hilo, wmlp2, B, 256, 256, 512, 512, b_mlp, nullptr,
          bufM, nullptr, nullptr, 256);
    hipMemsetAsync(stats, 0, 512 * sizeof(float), stream);
    bn_stats_kernel<<<256, 256, 0, stream>>>(bufM, B, stats);
    bn_apply_bf16_kernel<<<(B * 256 + 255) / 256, 256, 0, stream>>>(bufM, stats, g_si, be_si, B, e2_b);
    mgemm(e2_b, eh_b, B, NP3, N_HH, 256, 256, nullptr, nullptr,
          out, nullptr, nullptr, N_HH);
}

// Round 5
// 415.692 us; speedup vs baseline: 3.4070x; 1.0731x over previous
//
#include <hip/hip_runtime.h>
#include <cstddef>
#include <cstdint>

#define N_SH 1195
#define N_SS 390
#define N_HH 805
#define DIM  64

typedef __bf16 bf16_t;
typedef bf16_t bf16x4v __attribute__((ext_vector_type(4)));
typedef bf16_t bf16x8v __attribute__((ext_vector_type(8)));
typedef float f32x4 __attribute__((ext_vector_type(4)));

__device__ inline ushort f2bf(float f) {
    union { float f; uint32_t u; } c; c.f = f;
    uint32_t u = c.u;
    u += 0x7FFFu + ((u >> 16) & 1u);
    return (ushort)(u >> 16);
}

// bijective XCD swizzle (m204): consecutive tiles -> same XCD chunk
__device__ inline void xcd_swizzle(int gx, int gy, int& bx, int& by) {
    int nwg = gx * gy;
    int lin = by * gx + bx;
    int q = nwg >> 3, r = nwg & 7;
    int xcd = lin & 7, idx = lin >> 3;
    int nt = (xcd < r ? xcd * (q + 1) : r * (q + 1) + (xcd - r) * q) + idx;
    by = nt / gx; bx = nt % gx;
}

// ---------------- adjacency build (counts; exact & order-independent) -------
__global__ void build_adj_kernel(const int* __restrict__ ei, int E,
                                 float* __restrict__ A, int N) {
    int i = blockIdx.x * blockDim.x + threadIdx.x;
    if (i < E) {
        int src = ei[i];
        int dst = ei[E + i];
        atomicAdd(&A[(size_t)dst * N + src], 1.0f);
    }
}

__global__ void rowsum_inv_kernel(const float* __restrict__ X, int M, int K,
                                  float* __restrict__ inv, int use_max1) {
    int row  = blockIdx.x * (blockDim.x / 64) + (threadIdx.x / 64);
    int lane = threadIdx.x & 63;
    if (row >= M) return;
    const float* p = X + (size_t)row * K;
    float s = 0.f;
    for (int c = lane; c < K; c += 64) s += p[c];
    for (int off = 32; off > 0; off >>= 1) s += __shfl_down(s, off);
    if (lane == 0) {
        float d = use_max1 ? fmaxf(s, 1.0f) : s;
        inv[row] = 1.0f / d;
    }
}

// P[r][0:390] f32 -> P_b[r][0:416] bf16 (zero-pad) + presInv[r] = 1/rowsum
__global__ __launch_bounds__(128) void cvt_rowsum_p_kernel(
    const float* __restrict__ P, ushort* __restrict__ Pb,
    float* __restrict__ presInv)
{
    __shared__ float red[2];
    const int r = blockIdx.x;
    const int tid = threadIdx.x;
    float s = 0.f;
    #pragma unroll
    for (int it = 0; it < 4; ++it) {
        int c = tid + it * 128;
        float v = 0.f;
        if (c < N_SS) { v = P[(size_t)r * N_SS + c]; s += v; }
        if (c < 416) Pb[(size_t)r * 416 + c] = f2bf(v);
    }
    for (int off = 32; off > 0; off >>= 1) s += __shfl_down(s, off);
    if ((tid & 63) == 0) red[tid >> 6] = s;
    __syncthreads();
    if (tid == 0) {
        float t = red[0] + red[1];
        presInv[r] = (t != 0.f) ? 1.0f / t : 0.f;
    }
}

// ---------------- fp32 GEMM (small dense layers) ----------------------------
#define BM 64
#define BN 64
#define BK 16

__global__ __launch_bounds__(256) void gemm_kernel(
    const float* __restrict__ A, const float* __restrict__ B,
    const float* __restrict__ bias, const float* __restrict__ rowScale,
    float* __restrict__ C, int M, int N, int K, int act)
{
    __shared__ float As[BK][BM + 4];
    __shared__ float Bs[BK][BN];
    const int tid  = threadIdx.x;
    const int row0 = blockIdx.y * BM;
    const int col0 = blockIdx.x * BN;
    const int tr  = (tid >> 4) << 2;
    const int tc  = (tid & 15) << 2;
    const int lar = tid >> 2;
    const int lac = (tid & 3) << 2;
    const int lbr = tid >> 4;
    const int lbc = (tid & 15) << 2;

    float acc[4][4] = {{0.f}};

    for (int k0 = 0; k0 < K; k0 += BK) {
        const int gr = row0 + lar;
        const float* Ap = A + (size_t)gr * K + k0 + lac;
        #pragma unroll
        for (int i = 0; i < 4; ++i) {
            int gk = k0 + lac + i;
            As[lac + i][lar] = (gr < M && gk < K) ? Ap[i] : 0.f;
        }
        const int gk = k0 + lbr;
        const float* Bp = B + (size_t)gk * N + col0 + lbc;
        #pragma unroll
        for (int i = 0; i < 4; ++i) {
            int gc = col0 + lbc + i;
            Bs[lbr][lbc + i] = (gk < K && gc < N) ? Bp[i] : 0.f;
        }
        __syncthreads();
        #pragma unroll
        for (int kk = 0; kk < BK; ++kk) {
            float4 a = *reinterpret_cast<const float4*>(&As[kk][tr]);
            float4 b = *reinterpret_cast<const float4*>(&Bs[kk][tc]);
            acc[0][0] += a.x * b.x; acc[0][1] += a.x * b.y; acc[0][2] += a.x * b.z; acc[0][3] += a.x * b.w;
            acc[1][0] += a.y * b.x; acc[1][1] += a.y * b.y; acc[1][2] += a.y * b.z; acc[1][3] += a.y * b.w;
            acc[2][0] += a.z * b.x; acc[2][1] += a.z * b.y; acc[2][2] += a.z * b.z; acc[2][3] += a.z * b.w;
            acc[3][0] += a.w * b.x; acc[3][1] += a.w * b.y; acc[3][2] += a.w * b.z; acc[3][3] += a.w * b.w;
        }
        __syncthreads();
    }

    #pragma unroll
    for (int i = 0; i < 4; ++i) {
        int gr = row0 + tr + i;
        if (gr >= M) continue;
        float rs = rowScale ? rowScale[gr] : 1.0f;
        #pragma unroll
        for (int j = 0; j < 4; ++j) {
            int gc = col0 + tc + j;
            if (gc >= N) continue;
            float v = acc[i][j];
            if (bias) v += bias[gc];
            v *= rs;
            if (act == 1) v = tanhf(v);
            C[(size_t)gr * N + gc] = v;
        }
    }
}

// ---------------- bf16 MFMA GEMM: 128x128 tile, BK=32, 4 waves --------------
#define LDT 40

__global__ __launch_bounds__(256) void mfma_gemm_kernel(
    const ushort* __restrict__ A, const ushort* __restrict__ Bt,
    int M, int Nw, int K, int lda,
    const float* __restrict__ bias, const float* __restrict__ rowScale,
    float* __restrict__ outF, ushort* __restrict__ outB, ushort* __restrict__ outLo,
    int ldo)
{
    __shared__ __align__(16) ushort As[128 * LDT];
    __shared__ __align__(16) ushort Bs[128 * LDT];
    const int tid  = threadIdx.x;
    int bx = blockIdx.x, by = blockIdx.y;
    xcd_swizzle(gridDim.x, gridDim.y, bx, by);
    const int row0 = by * 128;
    const int col0 = bx * 128;
    const int wid  = tid >> 6, lane = tid & 63;
    const int wr = wid >> 1, wc = wid & 1;
    const int l15 = lane & 15, lg = lane >> 4;
    const int kg = lg * 4;
    const int sr = tid >> 2;
    const int sc = (tid & 3) * 8;

    f32x4 acc[4][4];
    #pragma unroll
    for (int m = 0; m < 4; ++m)
        #pragma unroll
        for (int n = 0; n < 4; ++n) acc[m][n] = (f32x4)0.f;

    for (int k0 = 0; k0 < K; k0 += 32) {
        const ushort* ga0 = A  + (size_t)(row0 + sr)      * lda + k0 + sc;
        const ushort* ga1 = A  + (size_t)(row0 + sr + 64) * lda + k0 + sc;
        const ushort* gb0 = Bt + (size_t)(col0 + sr)      * lda + k0 + sc;
        const ushort* gb1 = Bt + (size_t)(col0 + sr + 64) * lda + k0 + sc;
        *reinterpret_cast<uint4*>(&As[sr * LDT + sc])        = *reinterpret_cast<const uint4*>(ga0);
        *reinterpret_cast<uint4*>(&As[(sr + 64) * LDT + sc]) = *reinterpret_cast<const uint4*>(ga1);
        *reinterpret_cast<uint4*>(&Bs[sr * LDT + sc])        = *reinterpret_cast<const uint4*>(gb0);
        *reinterpret_cast<uint4*>(&Bs[(sr + 64) * LDT + sc]) = *reinterpret_cast<const uint4*>(gb1);
        __syncthreads();

        bf16x8v af[4], bfr[4];
        #pragma unroll
        for (int m = 0; m < 4; ++m) {
            int ar = wr * 64 + m * 16 + l15;
            bf16x4v lo = *reinterpret_cast<const bf16x4v*>(&As[ar * LDT + kg]);
            bf16x4v hi = *reinterpret_cast<const bf16x4v*>(&As[ar * LDT + kg + 16]);
            af[m] = __builtin_shufflevector(lo, hi, 0, 1, 2, 3, 4, 5, 6, 7);
        }
        #pragma unroll
        for (int n = 0; n < 4; ++n) {
            int br = wc * 64 + n * 16 + l15;
            bf16x4v lo = *reinterpret_cast<const bf16x4v*>(&Bs[br * LDT + kg]);
            bf16x4v hi = *reinterpret_cast<const bf16x4v*>(&Bs[br * LDT + kg + 16]);
            bfr[n] = __builtin_shufflevector(lo, hi, 0, 1, 2, 3, 4, 5, 6, 7);
        }
        #pragma unroll
        for (int m = 0; m < 4; ++m)
            #pragma unroll
            for (int n = 0; n < 4; ++n)
                acc[m][n] = __builtin_amdgcn_mfma_f32_16x16x32_bf16(af[m], bfr[n], acc[m][n], 0, 0, 0);
        __syncthreads();
    }

    #pragma unroll
    for (int m = 0; m < 4; ++m) {
        int grow_base = row0 + wr * 64 + m * 16 + kg;
        #pragma unroll
        for (int j = 0; j < 4; ++j) {
            int grow = grow_base + j;
            if (grow >= M) continue;
            float rs = rowScale ? rowScale[grow] : 1.0f;
            #pragma unroll
            for (int n = 0; n < 4; ++n) {
                int gcol = col0 + wc * 64 + n * 16 + l15;
                if (gcol >= Nw) continue;
                float v = acc[m][n][j];
                if (bias) v += bias[gcol];
                v *= rs;
                if (outB) {
                    ushort h = f2bf(v);
                    outB[(size_t)grow * ldo + gcol] = h;
                    if (outLo) {
                        float hv = __uint_as_float(((uint32_t)h) << 16);
                        outLo[(size_t)grow * ldo + gcol] = f2bf(v - hv);
                    }
                } else {
                    outF[(size_t)grow * ldo + gcol] = v;
                }
            }
        }
    }
}

// ---------------- C3: A = relu(bufM*scale+shift) staged f32->bf16, K=256 ----
__global__ __launch_bounds__(256) void mfma_c3_kernel(
    const float* __restrict__ Abuf, const ushort* __restrict__ Bt,
    int M, int Nw,
    const float* __restrict__ scale, const float* __restrict__ shift,
    float* __restrict__ outF, int ldo)
{
    __shared__ __align__(16) ushort As[128 * LDT];
    __shared__ __align__(16) ushort Bs[128 * LDT];
    const int tid  = threadIdx.x;
    int bx = blockIdx.x, by = blockIdx.y;
    xcd_swizzle(gridDim.x, gridDim.y, bx, by);
    const int row0 = by * 128;
    const int col0 = bx * 128;
    const int wid  = tid >> 6, lane = tid & 63;
    const int wr = wid >> 1, wc = wid & 1;
    const int l15 = lane & 15, lg = lane >> 4;
    const int kg = lg * 4;
    const int sr = tid >> 2;
    const int sc = (tid & 3) * 8;

    f32x4 acc[4][4];
    #pragma unroll
    for (int m = 0; m < 4; ++m)
        #pragma unroll
        for (int n = 0; n < 4; ++n) acc[m][n] = (f32x4)0.f;

    for (int k0 = 0; k0 < 256; k0 += 32) {
        // A: read f32, BN+relu, convert
        float sc8[8], sh8[8];
        #pragma unroll
        for (int i = 0; i < 8; ++i) { sc8[i] = scale[k0 + sc + i]; sh8[i] = shift[k0 + sc + i]; }
        #pragma unroll
        for (int half = 0; half < 2; ++half) {
            const float* ga = Abuf + (size_t)(row0 + sr + half * 64) * 256 + k0 + sc;
            float4 v0 = *reinterpret_cast<const float4*>(ga);
            float4 v1 = *reinterpret_cast<const float4*>(ga + 4);
            ushort h[8];
            h[0] = f2bf(fmaxf(v0.x * sc8[0] + sh8[0], 0.f));
            h[1] = f2bf(fmaxf(v0.y * sc8[1] + sh8[1], 0.f));
            h[2] = f2bf(fmaxf(v0.z * sc8[2] + sh8[2], 0.f));
            h[3] = f2bf(fmaxf(v0.w * sc8[3] + sh8[3], 0.f));
            h[4] = f2bf(fmaxf(v1.x * sc8[4] + sh8[4], 0.f));
            h[5] = f2bf(fmaxf(v1.y * sc8[5] + sh8[5], 0.f));
            h[6] = f2bf(fmaxf(v1.z * sc8[6] + sh8[6], 0.f));
            h[7] = f2bf(fmaxf(v1.w * sc8[7] + sh8[7], 0.f));
            *reinterpret_cast<uint4*>(&As[(sr + half * 64) * LDT + sc]) =
                *reinterpret_cast<const uint4*>(h);
        }
        const ushort* gb0 = Bt + (size_t)(col0 + sr)      * 256 + k0 + sc;
        const ushort* gb1 = Bt + (size_t)(col0 + sr + 64) * 256 + k0 + sc;
        *reinterpret_cast<uint4*>(&Bs[sr * LDT + sc])        = *reinterpret_cast<const uint4*>(gb0);
        *reinterpret_cast<uint4*>(&Bs[(sr + 64) * LDT + sc]) = *reinterpret_cast<const uint4*>(gb1);
        __syncthreads();

        bf16x8v af[4], bfr[4];
        #pragma unroll
        for (int m = 0; m < 4; ++m) {
            int ar = wr * 64 + m * 16 + l15;
            bf16x4v lo = *reinterpret_cast<const bf16x4v*>(&As[ar * LDT + kg]);
            bf16x4v hi = *reinterpret_cast<const bf16x4v*>(&As[ar * LDT + kg + 16]);
            af[m] = __builtin_shufflevector(lo, hi, 0, 1, 2, 3, 4, 5, 6, 7);
        }
        #pragma unroll
        for (int n = 0; n < 4; ++n) {
            int br = wc * 64 + n * 16 + l15;
            bf16x4v lo = *reinterpret_cast<const bf16x4v*>(&Bs[br * LDT + kg]);
            bf16x4v hi = *reinterpret_cast<const bf16x4v*>(&Bs[br * LDT + kg + 16]);
            bfr[n] = __builtin_shufflevector(lo, hi, 0, 1, 2, 3, 4, 5, 6, 7);
        }
        #pragma unroll
        for (int m = 0; m < 4; ++m)
            #pragma unroll
            for (int n = 0; n < 4; ++n)
                acc[m][n] = __builtin_amdgcn_mfma_f32_16x16x32_bf16(af[m], bfr[n], acc[m][n], 0, 0, 0);
        __syncthreads();
    }

    #pragma unroll
    for (int m = 0; m < 4; ++m) {
        int grow_base = row0 + wr * 64 + m * 16 + kg;
        #pragma unroll
        for (int j = 0; j < 4; ++j) {
            int grow = grow_base + j;
            if (grow >= M) continue;
            #pragma unroll
            for (int n = 0; n < 4; ++n) {
                int gcol = col0 + wc * 64 + n * 16 + l15;
                if (gcol >= Nw) continue;
                outF[(size_t)grow * ldo + gcol] = acc[m][n][j];
            }
        }
    }
}

// ---------------- split-K MFMA: partials (f32), grid.z = K-chunk ------------
__global__ __launch_bounds__(256) void mfma_splitk_kernel(
    const ushort* __restrict__ A, const ushort* __restrict__ Bt,
    int M, int K, int lda, int kChunk, int Ntot,
    float* __restrict__ part)
{
    __shared__ __align__(16) ushort As[128 * LDT];
    __shared__ __align__(16) ushort Bs[128 * LDT];
    const int tid  = threadIdx.x;
    const int row0 = blockIdx.y * 128;
    const int col0 = blockIdx.x * 128;
    const int wid  = tid >> 6, lane = tid & 63;
    const int wr = wid >> 1, wc = wid & 1;
    const int l15 = lane & 15, lg = lane >> 4;
    const int kg = lg * 4;
    const int sr = tid >> 2;
    const int sc = (tid & 3) * 8;

    const int k0s = blockIdx.z * kChunk;
    const int k0e = (k0s + kChunk < K) ? k0s + kChunk : K;

    f32x4 acc[4][4];
    #pragma unroll
    for (int m = 0; m < 4; ++m)
        #pragma unroll
        for (int n = 0; n < 4; ++n) acc[m][n] = (f32x4)0.f;

    for (int k0 = k0s; k0 < k0e; k0 += 32) {
        const ushort* ga0 = A  + (size_t)(row0 + sr)      * lda + k0 + sc;
        const ushort* ga1 = A  + (size_t)(row0 + sr + 64) * lda + k0 + sc;
        const ushort* gb0 = Bt + (size_t)(col0 + sr)      * lda + k0 + sc;
        const ushort* gb1 = Bt + (size_t)(col0 + sr + 64) * lda + k0 + sc;
        *reinterpret_cast<uint4*>(&As[sr * LDT + sc])        = *reinterpret_cast<const uint4*>(ga0);
        *reinterpret_cast<uint4*>(&As[(sr + 64) * LDT + sc]) = *reinterpret_cast<const uint4*>(ga1);
        *reinterpret_cast<uint4*>(&Bs[sr * LDT + sc])        = *reinterpret_cast<const uint4*>(gb0);
        *reinterpret_cast<uint4*>(&Bs[(sr + 64) * LDT + sc]) = *reinterpret_cast<const uint4*>(gb1);
        __syncthreads();

        bf16x8v af[4], bfr[4];
        #pragma unroll
        for (int m = 0; m < 4; ++m) {
            int ar = wr * 64 + m * 16 + l15;
            bf16x4v lo = *reinterpret_cast<const bf16x4v*>(&As[ar * LDT + kg]);
            bf16x4v hi = *reinterpret_cast<const bf16x4v*>(&As[ar * LDT + kg + 16]);
            af[m] = __builtin_shufflevector(lo, hi, 0, 1, 2, 3, 4, 5, 6, 7);
        }
        #pragma unroll
        for (int n = 0; n < 4; ++n) {
            int br = wc * 64 + n * 16 + l15;
            bf16x4v lo = *reinterpret_cast<const bf16x4v*>(&Bs[br * LDT + kg]);
            bf16x4v hi = *reinterpret_cast<const bf16x4v*>(&Bs[br * LDT + kg + 16]);
            bfr[n] = __builtin_shufflevector(lo, hi, 0, 1, 2, 3, 4, 5, 6, 7);
        }
        #pragma unroll
        for (int m = 0; m < 4; ++m)
            #pragma unroll
            for (int n = 0; n < 4; ++n)
                acc[m][n] = __builtin_amdgcn_mfma_f32_16x16x32_bf16(af[m], bfr[n], acc[m][n], 0, 0, 0);
        __syncthreads();
    }

    float* pslab = part + (size_t)blockIdx.z * M * Ntot;
    #pragma unroll
    for (int m = 0; m < 4; ++m) {
        int grow_base = row0 + wr * 64 + m * 16 + kg;
        #pragma unroll
        for (int j = 0; j < 4; ++j) {
            int grow = grow_base + j;
            if (grow >= M) continue;
            #pragma unroll
            for (int n = 0; n < 4; ++n) {
                int gcol = col0 + wc * 64 + n * 16 + l15;
                pslab[(size_t)grow * Ntot + gcol] = acc[m][n][j];
            }
        }
    }
}

__global__ void reduce_tanh_kernel(const float* __restrict__ part, int S, int M, int N,
                                   const float* __restrict__ rs, float* __restrict__ out) {
    int i = blockIdx.x * blockDim.x + threadIdx.x;
    if (i >= M * N) return;
    int r = i / N;
    float s = 0.f;
    for (int z = 0; z < S; ++z) s += part[(size_t)z * M * N + i];
    if (rs) s *= rs[r];
    out[i] = tanhf(s);
}

// ---------------- conversion / fusion helpers -------------------------------
__global__ void cvt_pad2_kernel(const float* __restrict__ in, int R, int C,
                                ushort* __restrict__ out, int Rp, int Cp) {
    int i = blockIdx.x * blockDim.x + threadIdx.x;
    if (i >= Rp * Cp) return;
    int r = i / Cp, c = i % Cp;
    float v = (r < R && c < C) ? in[(size_t)r * C + c] : 0.f;
    out[i] = f2bf(v);
}

__global__ void transpose_cvt_kernel(const float* __restrict__ in, int K, int N, int ldin,
                                     ushort* __restrict__ out, int Kp) {
    int i = blockIdx.x * blockDim.x + threadIdx.x;
    if (i >= N * Kp) return;
    int n = i / Kp, k = i % Kp;
    float v = (k < K) ? in[(size_t)k * ldin + n] : 0.f;
    out[i] = f2bf(v);
}

__global__ void make_cat_weights_kernel(
    const float* __restrict__ w_sh1, const float* __restrict__ w_sh1h,
    const float* __restrict__ b_sh1, const float* __restrict__ b_sh1h,
    const float* __restrict__ w_sh2, const float* __restrict__ w_sh2h,
    const float* __restrict__ b_sh2, const float* __restrict__ b_sh2h,
    const float* __restrict__ w_mlp1, const float* __restrict__ w_mlp1h,
    const float* __restrict__ b_mlp1, const float* __restrict__ b_mlp1h,
    float* __restrict__ W1cat, float* __restrict__ b1cat,
    float* __restrict__ W2bd,  float* __restrict__ b2cat,
    float* __restrict__ WMbd,  float* __restrict__ bMcat)
{
    int i = blockIdx.x * blockDim.x + threadIdx.x;
    if (i < 64 * 128) {
        int k = i >> 7, j = i & 127;
        W1cat[i] = (j < 64) ? w_sh1[k * 64 + j] : w_sh1h[k * 64 + (j - 64)];
        return;
    }
    i -= 64 * 128;
    if (i < 128) { b1cat[i] = (i < 64) ? b_sh1[i] : b_sh1h[i - 64]; return; }
    i -= 128;
    if (i < 128 * 128) {
        int k = i >> 7, j = i & 127;
        float v = 0.f;
        if (k < 64 && j < 64) v = w_sh2[k * 64 + j];
        else if (k >= 64 && j >= 64) v = w_sh2h[(k - 64) * 64 + (j - 64)];
        W2bd[i] = v;
        return;
    }
    i -= 128 * 128;
    if (i < 128) { b2cat[i] = (i < 64) ? b_sh2[i] : b_sh2h[i - 64]; return; }
    i -= 128;
    if (i < 128 * 512) {
        int k = i >> 9, j = i & 511;
        float v = 0.f;
        if (j < 256) { if (k < 64) v = w_mlp1[k * 256 + j]; }
        else         { if (k >= 64) v = w_mlp1h[(k - 64) * 256 + (j - 256)]; }
        WMbd[i] = v;
        return;
    }
    i -= 128 * 512;
    if (i < 512) { bMcat[i] = (i < 256) ? b_mlp1[i] : b_mlp1h[i - 256]; }
}

__global__ void avg3cat_kernel(const float* __restrict__ emb, const float* __restrict__ x2cat,
                               const float* __restrict__ x6cat, float* __restrict__ o) {
    int i = blockIdx.x * blockDim.x + threadIdx.x;
    if (i >= N_SH * 128) return;
    int r = i >> 7, j = i & 127;
    o[i] = (emb[r * 64 + (j & 63)] + x2cat[i] + x6cat[i]) * (1.0f / 3.0f);
}

__global__ void concat_hh_kernel(const float* __restrict__ emb, const float* __restrict__ kg,
                                 float* __restrict__ out) {
    int i = blockIdx.x * blockDim.x + threadIdx.x;
    const int n = N_HH * 91;
    if (i >= n) return;
    int r = i / 91, c = i % 91;
    out[i] = (c < DIM) ? emb[r * DIM + c] : kg[r * 27 + (c - DIM)];
}

__global__ void make_esbt_kernel(const float* __restrict__ x9cat, const float* __restrict__ ss1,
                                 ushort* __restrict__ out, int Kp) {
    int i = blockIdx.x * blockDim.x + threadIdx.x;
    if (i >= 256 * Kp) return;
    int n = i / Kp, k = i % Kp;
    float v = (k < N_SS) ? (x9cat[(size_t)k * 512 + n] + ss1[(size_t)k * 256 + n]) : 0.f;
    out[i] = f2bf(v);
}

__global__ void make_wmlp2_kernel(const float* __restrict__ wm, ushort* __restrict__ out) {
    int i = blockIdx.x * blockDim.x + threadIdx.x;
    if (i >= 256 * 512) return;
    int n = i >> 9, k = i & 511;
    out[i] = f2bf(wm[(size_t)(k & 255) * 256 + n]);
}

__global__ void make_ehb_kernel(const float* __restrict__ x9cat, const float* __restrict__ hh1,
                                ushort* __restrict__ out, int Rp) {
    int i = blockIdx.x * blockDim.x + threadIdx.x;
    if (i >= Rp * 256) return;
    int r = i >> 8, c = i & 255;
    float v = (r < N_HH) ? (x9cat[(size_t)(N_SS + r) * 512 + 256 + c] + hh1[(size_t)r * 256 + c]) : 0.f;
    out[i] = f2bf(v);
}

// ---------------- BatchNorm -------------------------------------------------
__global__ void bn_stats_cat_kernel(const float* __restrict__ X, int M,
                                    float* __restrict__ stats) {
    int j = threadIdx.x;  // 512
    float s = 0.f, ss = 0.f;
    for (int r = blockIdx.x; r < M; r += gridDim.x) {
        float v = X[(size_t)r * 512 + j];
        s += v; ss += v * v;
    }
    atomicAdd(&stats[j], s);
    atomicAdd(&stats[512 + j], ss);
}

__global__ void bn_apply_cat_kernel(const float* __restrict__ X, const float* __restrict__ stats,
                                    const float* __restrict__ g1, const float* __restrict__ be1,
                                    const float* __restrict__ g2, const float* __restrict__ be2,
                                    int M, float* __restrict__ out) {
    int i = blockIdx.x * blockDim.x + threadIdx.x;
    if (i >= M * 512) return;
    int j = i & 511;
    float invM = 1.0f / (float)M;
    float mean = stats[j] * invM;
    float var  = fmaxf(stats[512 + j] * invM - mean * mean, 0.f);
    float ga = (j < 256) ? g1[j]  : g2[j - 256];
    float bb = (j < 256) ? be1[j] : be2[j - 256];
    float y = (X[i] - mean) * rsqrtf(var + 1e-5f) * ga + bb;
    out[i] = tanhf(y);
}

__global__ void bn_stats_kernel(const float* __restrict__ X, int M,
                                float* __restrict__ stats) {
    int j = threadIdx.x;
    float s = 0.f, ss = 0.f;
    for (int r = blockIdx.x; r < M; r += gridDim.x) {
        float v = X[(size_t)r * 256 + j];
        s += v; ss += v * v;
    }
    atomicAdd(&stats[j], s);
    atomicAdd(&stats[256 + j], ss);
}

// stats -> scale/shift for fused BN+relu staging
__global__ void bn_finalize_kernel(const float* __restrict__ stats,
                                   const float* __restrict__ g, const float* __restrict__ be,
                                   int M, float* __restrict__ scale, float* __restrict__ shift) {
    int j = threadIdx.x;  // 256
    float invM = 1.0f / (float)M;
    float mean = stats[j] * invM;
    float var  = fmaxf(stats[256 + j] * invM - mean * mean, 0.f);
    float sc = g[j] * rsqrtf(var + 1e-5f);
    scale[j] = sc;
    shift[j] = be[j] - mean * sc;
}

// ---------------- driver -----------------------------------------------------
extern "C" void kernel_launch(void* const* d_in, const int* in_sizes, int n_in,
                              void* d_out, int out_size, void* d_ws, size_t ws_size,
                              hipStream_t stream) {
    const int*   eiSH = (const int*)d_in[1];
    const int*   eiSS = (const int*)d_in[3];
    const int*   eiHH = (const int*)d_in[5];
    const float* P    = (const float*)d_in[6];
    const float* kg   = (const float*)d_in[7];
    const float* emb  = (const float*)d_in[8];
    const float* w_sh1  = (const float*)d_in[9];   const float* b_sh1  = (const float*)d_in[10];
    const float* w_sh2  = (const float*)d_in[11];  const float* b_sh2  = (const float*)d_in[12];
    const float* w_mlp1 = (const float*)d_in[13];  const float* b_mlp1 = (const float*)d_in[14];
    const float* g_bn1  = (const float*)d_in[15];  const float* be_bn1 = (const float*)d_in[16];
    const float* w_sh1h = (const float*)d_in[17];  const float* b_sh1h = (const float*)d_in[18];
    const float* w_sh2h = (const float*)d_in[19];  const float* b_sh2h = (const float*)d_in[20];
    const float* w_mlp1h= (const float*)d_in[21];  const float* b_mlp1h= (const float*)d_in[22];
    const float* g_bn1h = (const float*)d_in[23];  const float* be_bn1h= (const float*)d_in[24];
    const float* w_ss   = (const float*)d_in[25];  const float* b_ss   = (const float*)d_in[26];
    const float* w_hh   = (const float*)d_in[27];  const float* b_hh   = (const float*)d_in[28];
    const float* w_mlp  = (const float*)d_in[29];  const float* b_mlp  = (const float*)d_in[30];
    const float* g_si   = (const float*)d_in[31];  const float* be_si  = (const float*)d_in[32];
    float* out = (float*)d_out;

    const int E_SH = in_sizes[1] / 2;
    const int E_SS = in_sizes[3] / 2;
    const int E_HH = in_sizes[5] / 2;
    const int B    = in_sizes[6] / N_SS;      // 20000
    const int Mp   = ((B + 127) / 128) * 128; // 20096
    const int KP1  = 416;
    const int NP3  = 896;
    const int KSH  = 1216;
    const int KHH  = 832;

    float* w = (float*)d_ws;
    size_t off = 0;
    auto alloc = [&](size_t n) { float* p = w + off; off += (n + 3) & ~(size_t)3; return p; };

    float* cntInv  = alloc(N_SH);
    float* presInv = alloc(B);
    float* stats   = alloc(1024);
    float* bnScale = alloc(256);
    float* bnShift = alloc(256);
    float* W1cat   = alloc(64 * 128);
    float* b1cat   = alloc(128);
    float* W2bd    = alloc(128 * 128);
    float* b2cat   = alloc(128);
    float* WMbd    = alloc(128 * 512);
    float* bMcat   = alloc(512);
    ushort* adjb   = (ushort*)alloc((size_t)1280 * KSH / 2);
    ushort* adjSSb = (ushort*)alloc((size_t)512 * KP1 / 2);
    ushort* adjHHb = (ushort*)alloc((size_t)896 * KHH / 2);
    float* tmpL    = alloc((size_t)N_SH * 128);
    ushort* HT     = (ushort*)alloc((size_t)128 * KSH / 2);
    float* x2cat   = alloc((size_t)N_SH * 128);
    float* x6cat   = alloc((size_t)N_SH * 128);
    float* x9a2    = alloc((size_t)N_SH * 128);
    float* tmpBN   = alloc((size_t)N_SH * 512);
    float* x9cat   = alloc((size_t)N_SH * 512);
    float* ss1     = alloc((size_t)N_SS * 256);
    float* hh1     = alloc((size_t)N_HH * 256);
    float* xhh0    = alloc((size_t)N_HH * 91);
    ushort* HSST   = (ushort*)alloc((size_t)256 * KP1 / 2);
    ushort* HHHT   = (ushort*)alloc((size_t)256 * KHH / 2);
    ushort* es_bT  = (ushort*)alloc((size_t)256 * KP1 / 2);
    ushort* wmlp2  = (ushort*)alloc((size_t)256 * 512 / 2);
    ushort* eh_b   = (ushort*)alloc((size_t)NP3 * 256 / 2);
    // region A: f32 adjacency (early) -> P_b bf16 [Mp][416] -> bufM f32 [Mp][256]
    float* regionA = alloc((size_t)Mp * 256);
    float* adjSH   = regionA;
    float* adjSS   = regionA + (size_t)N_SH * N_SH;
    float* adjHH   = adjSS + (size_t)N_SS * N_SS;
    ushort* P_b    = (ushort*)regionA;
    float*  bufM   = regionA;
    // region B: split-K partials (early) -> e_hilo bf16 [Mp][512]
    float* regionB = alloc((size_t)Mp * 256);
    float*  partials = regionB;
    ushort* e_hilo = (ushort*)regionB;
    (void)ws_size; (void)n_in; (void)out_size;

    auto gemm = [&](const float* Am, const float* Bm, const float* bias, const float* rs,
                    float* C, int M, int N, int K, int act) {
        dim3 g((N + BN - 1) / BN, (M + BM - 1) / BM);
        gemm_kernel<<<g, 256, 0, stream>>>(Am, Bm, bias, rs, C, M, N, K, act);
    };
    auto mgemm = [&](const ushort* Am, const ushort* Bm, int M, int Np, int Nw, int K, int lda,
                     const float* bias, const float* rs,
                     float* oF, ushort* oB, ushort* oLo, int ldo) {
        dim3 g(Np / 128, (M + 127) / 128);
        mfma_gemm_kernel<<<g, 256, 0, stream>>>(Am, Bm, M, Nw, K, lda, bias, rs, oF, oB, oLo, ldo);
    };
    auto splitk = [&](const ushort* Am, const ushort* Bm, int M, int Mtiles, int K, int lda,
                      int Ntot, int S, const float* rs, float* outp) {
        dim3 g(Ntot / 128, Mtiles, S);
        mfma_splitk_kernel<<<g, 256, 0, stream>>>(Am, Bm, M, K, lda, 128, Ntot, partials);
        reduce_tanh_kernel<<<(M * Ntot + 255) / 256, 256, 0, stream>>>(partials, S, M, Ntot, rs, outp);
    };

    // ---- adjacency ----
    hipMemsetAsync(regionA, 0,
                   ((size_t)N_SH * N_SH + (size_t)N_SS * N_SS + (size_t)N_HH * N_HH + 16) * sizeof(float),
                   stream);
    build_adj_kernel<<<(E_SH + 255) / 256, 256, 0, stream>>>(eiSH, E_SH, adjSH, N_SH);
    build_adj_kernel<<<(E_SS + 255) / 256, 256, 0, stream>>>(eiSS, E_SS, adjSS, N_SS);
    build_adj_kernel<<<(E_HH + 255) / 256, 256, 0, stream>>>(eiHH, E_HH, adjHH, N_HH);
    rowsum_inv_kernel<<<(N_SH + 3) / 4, 256, 0, stream>>>(adjSH, N_SH, N_SH, cntInv, 1);
    cvt_pad2_kernel<<<(1280 * KSH + 255) / 256, 256, 0, stream>>>(adjSH, N_SH, N_SH, adjb, 1280, KSH);
    cvt_pad2_kernel<<<(512 * KP1 + 255) / 256, 256, 0, stream>>>(adjSS, N_SS, N_SS, adjSSb, 512, KP1);
    cvt_pad2_kernel<<<(896 * KHH + 255) / 256, 256, 0, stream>>>(adjHH, N_HH, N_HH, adjHHb, 896, KHH);

    make_cat_weights_kernel<<<(90880 + 255) / 256, 256, 0, stream>>>(
        w_sh1, w_sh1h, b_sh1, b_sh1h, w_sh2, w_sh2h, b_sh2, b_sh2h,
        w_mlp1, w_mlp1h, b_mlp1, b_mlp1h,
        W1cat, b1cat, W2bd, b2cat, WMbd, bMcat);

    // ---- SH layers (fused branches) ----
    gemm(emb, W1cat, b1cat, nullptr, tmpL, N_SH, 128, 64, 0);
    transpose_cvt_kernel<<<(128 * KSH + 255) / 256, 256, 0, stream>>>(tmpL, N_SH, 128, 128, HT, KSH);
    splitk(adjb, HT, N_SH, 10, KSH, KSH, 128, 10, cntInv, x2cat);
    gemm(x2cat, W2bd, b2cat, nullptr, tmpL, N_SH, 128, 128, 0);
    transpose_cvt_kernel<<<(128 * KSH + 255) / 256, 256, 0, stream>>>(tmpL, N_SH, 128, 128, HT, KSH);
    splitk(adjb, HT, N_SH, 10, KSH, KSH, 128, 10, cntInv, x6cat);
    avg3cat_kernel<<<(N_SH * 128 + 255) / 256, 256, 0, stream>>>(emb, x2cat, x6cat, x9a2);
    gemm(x9a2, WMbd, bMcat, nullptr, tmpBN, N_SH, 512, 128, 0);
    hipMemsetAsync(stats, 0, 1024 * sizeof(float), stream);
    bn_stats_cat_kernel<<<64, 512, 0, stream>>>(tmpBN, N_SH, stats);
    bn_apply_cat_kernel<<<(N_SH * 512 + 255) / 256, 256, 0, stream>>>(
        tmpBN, stats, g_bn1, be_bn1, g_bn1h, be_bn1h, N_SH, x9cat);

    // ---- SS graph ----
    gemm(emb, w_ss, b_ss, nullptr, tmpBN, N_SS, 256, 64, 0);
    transpose_cvt_kernel<<<(256 * KP1 + 255) / 256, 256, 0, stream>>>(tmpBN, N_SS, 256, 256, HSST, KP1);
    splitk(adjSSb, HSST, N_SS, 4, KP1, KP1, 256, 4, nullptr, ss1);

    // ---- HH graph ----
    concat_hh_kernel<<<(N_HH * 91 + 255) / 256, 256, 0, stream>>>(emb, kg, xhh0);
    gemm(xhh0, w_hh, b_hh, nullptr, tmpBN, N_HH, 256, 91, 0);
    transpose_cvt_kernel<<<(256 * KHH + 255) / 256, 256, 0, stream>>>(tmpBN, N_HH, 256, 256, HHHT, KHH);
    splitk(adjHHb, HHHT, N_HH, 7, KHH, KHH, 256, 7, nullptr, hh1);

    // ---- prepare bf16 operands for prescription path ----
    make_esbt_kernel<<<(256 * KP1 + 255) / 256, 256, 0, stream>>>(x9cat, ss1, es_bT, KP1);
    make_wmlp2_kernel<<<(256 * 512 + 255) / 256, 256, 0, stream>>>(w_mlp, wmlp2);
    make_ehb_kernel<<<(NP3 * 256 + 255) / 256, 256, 0, stream>>>(x9cat, hh1, eh_b, NP3);
    cvt_rowsum_p_kernel<<<B, 128, 0, stream>>>(P, P_b, presInv);

    // ---- prescription path (bf16 MFMA) ----
    // C1: e = (P @ es) * presInv -> hi/lo bf16 pair [Mp][512]
    mgemm(P_b, es_bT, B, 256, 256, KP1, KP1, nullptr, presInv,
          nullptr, e_hilo, e_hilo + 256, 512);
    // C2: bufM = (e_hi + e_lo) @ w_mlp + b_mlp  (K=512, duplicated w^T)
    mgemm(e_hilo, wmlp2, B, 256, 256, 512, 512, b_mlp, nullptr,
          bufM, nullptr, nullptr, 256);
    // BN stats -> scale/shift
    hipMemsetAsync(stats, 0, 512 * sizeof(float), stream);
    bn_stats_kernel<<<256, 256, 0, stream>>>(bufM, B, stats);
    bn_finalize_kernel<<<1, 256, 0, stream>>>(stats, g_si, be_si, B, bnScale, bnShift);
    // C3: out = relu(BN(bufM)) @ eh^T   (BN fused into A-staging)
    {
        dim3 g(NP3 / 128, (B + 127) / 128);
        mfma_c3_kernel<<<g, 256, 0, stream>>>(bufM, eh_b, B, N_HH, bnScale, bnShift, out, N_HH);
    }
}